// Round 1
// baseline (839.108 us; speedup 1.0000x reference)
//
#include <hip/hip_runtime.h>

#define DEVFN __device__ __forceinline__

DEVFN float sgnf(float x) { return (x > 0.f) ? 1.f : ((x < 0.f) ? -1.f : 0.f); }

DEVFN float wave_sum(float v) {
#pragma unroll
  for (int off = 32; off > 0; off >>= 1) v += __shfl_down(v, off, 64);
  return v;  // lane 0 of each wave holds the wave total
}

// ---- workspace layout ----
// double region (BN stat accumulators, 64 contention slots per channel)
#define SUM1 0        // 6*64 doubles
#define SQ1  384
#define SUM2 768      // 16*64
#define SQ2  1792
#define SUM3 2816     // 120*64
#define SQ3  10496
#define DBL_BYTES 145408  // 18176 doubles

// float region offsets (in floats, from fbase = ws + DBL_BYTES)
#define A1 0
#define C1 8
#define A2 16
#define C2 32
#define A3 48
#define C3 168
#define W2B_OFF  512                    // 2400
#define W3BT_OFF 2912                   // 48000, layout [400][120]
#define FC1B_OFF 50912                  // 10080
#define H1_OFF   61440                  // 8192*1176
#define H2_OFF   (H1_OFF + 8192*1176)   // 8192*400
#define Y3_OFF   (H2_OFF + 8192*400)    // 8192*120

// ---------------- binarize weights ----------------
__global__ __launch_bounds__(256) void binarize_k(
    const float* __restrict__ w2, const float* __restrict__ w3,
    const float* __restrict__ f1, float* __restrict__ w2b,
    float* __restrict__ w3bT, float* __restrict__ f1b) {
  int i = blockIdx.x * 256 + threadIdx.x;
  if (i < 2400) w2b[i] = sgnf(w2[i]);
  if (i < 48000) {
    int c = i / 400, j = i - c * 400;
    w3bT[j * 120 + c] = sgnf(w3[i]);  // transpose for coalesced conv3 reads
  }
  if (i < 10080) f1b[i] = sgnf(f1[i]);
}

// ---------------- layer 1 phase A: conv + stats ----------------
__global__ __launch_bounds__(256) void conv1_stats(
    const float* __restrict__ x, const float* __restrict__ w1,
    const float* __restrict__ b1, double* __restrict__ sums) {
  __shared__ float simg[8 * 1024];
  __shared__ float swt[150];
  __shared__ float sb[6];
  __shared__ float red[12];
  int tid = threadIdx.x;
  int img0 = blockIdx.x * 8;
  for (int i = tid; i < 8192; i += 256) simg[i] = x[img0 * 1024 + i];
  if (tid < 150) swt[tid] = w1[tid];
  if (tid < 6) sb[tid] = b1[tid];
  if (tid < 12) red[tid] = 0.f;
  __syncthreads();
  for (int c = 0; c < 6; ++c) {
    float wr[25];
#pragma unroll
    for (int k = 0; k < 25; ++k) wr[k] = swt[c * 25 + k];
    float bb = sb[c];
    float s = 0.f, s2 = 0.f;
    for (int ip = tid; ip < 8 * 784; ip += 256) {
      int img = ip / 784;
      int p = ip - img * 784;
      int oy = p / 28;
      int ox = p - oy * 28;
      const float* base = &simg[img * 1024 + oy * 32 + ox];
      float acc = bb;
#pragma unroll
      for (int ky = 0; ky < 5; ++ky)
#pragma unroll
        for (int kx = 0; kx < 5; ++kx)
          acc = fmaf(base[ky * 32 + kx], wr[ky * 5 + kx], acc);
      s += acc;
      s2 += acc * acc;
    }
    s = wave_sum(s);
    s2 = wave_sum(s2);
    if ((tid & 63) == 0) {
      atomicAdd(&red[c], s);
      atomicAdd(&red[6 + c], s2);
    }
  }
  __syncthreads();
  if (tid < 6) {
    int slot = blockIdx.x & 63;
    atomicAdd(&sums[SUM1 + tid * 64 + slot], (double)red[tid]);
    atomicAdd(&sums[SQ1 + tid * 64 + slot], (double)red[6 + tid]);
  }
}

// ---------------- BN finalize: a = g*rsqrt(var+eps), c = beta - mean*a ------
__global__ __launch_bounds__(128) void finalize_bn(
    const double* __restrict__ sum, const double* __restrict__ sq, int nch,
    double invN, double eps, const float* __restrict__ gamma,
    const float* __restrict__ beta, float* __restrict__ a,
    float* __restrict__ c) {
  int ch = threadIdx.x;
  if (ch >= nch) return;
  double s = 0.0, q = 0.0;
  for (int k = 0; k < 64; ++k) {
    s += sum[ch * 64 + k];
    q += sq[ch * 64 + k];
  }
  double mean = s * invN;
  double var = q * invN - mean * mean;
  float inv = (float)(1.0 / sqrt(var + eps));
  float g = gamma ? fmaxf(gamma[ch], 0.01f) : 1.f;
  float av = g * inv;
  float cv = (beta ? beta[ch] : 0.f) - (float)mean * av;
  a[ch] = av;
  c[ch] = cv;
}

// ---------------- layer 1 phase B: conv(recompute) + BN + relu + maxpool ----
__global__ __launch_bounds__(256) void conv1_pool(
    const float* __restrict__ x, const float* __restrict__ w1,
    const float* __restrict__ b1, const float* __restrict__ scales,
    float* __restrict__ h1) {
  __shared__ float simg[8 * 1024];
  __shared__ float swt[150];
  __shared__ float sa[6], sc[6], sb[6];
  int tid = threadIdx.x;
  int img0 = blockIdx.x * 8;
  for (int i = tid; i < 8192; i += 256) simg[i] = x[img0 * 1024 + i];
  if (tid < 150) swt[tid] = w1[tid];
  if (tid < 6) {
    sa[tid] = scales[A1 + tid];
    sc[tid] = scales[C1 + tid];
    sb[tid] = b1[tid];
  }
  __syncthreads();
  for (int idx = tid; idx < 8 * 1176; idx += 256) {
    int img = idx / 1176;
    int r = idx - img * 1176;
    int c = r / 196;
    int p = r - c * 196;
    int py = p / 14, px = p - py * 14;
    int iy = py * 2, ix = px * 2;
    const float* base = &simg[img * 1024 + iy * 32 + ix];
    float win[36];
#pragma unroll
    for (int r6 = 0; r6 < 6; ++r6)
#pragma unroll
      for (int c6 = 0; c6 < 6; ++c6) win[r6 * 6 + c6] = base[r6 * 32 + c6];
    float m0, m1, m2, m3;
    m0 = m1 = m2 = m3 = sb[c];
#pragma unroll
    for (int ky = 0; ky < 5; ++ky)
#pragma unroll
      for (int kx = 0; kx < 5; ++kx) {
        float wv = swt[c * 25 + ky * 5 + kx];
        m0 = fmaf(win[ky * 6 + kx], wv, m0);
        m1 = fmaf(win[ky * 6 + kx + 1], wv, m1);
        m2 = fmaf(win[(ky + 1) * 6 + kx], wv, m2);
        m3 = fmaf(win[(ky + 1) * 6 + kx + 1], wv, m3);
      }
    float m = fmaxf(fmaxf(m0, m1), fmaxf(m2, m3));
    h1[(img0 + img) * 1176 + r] = fmaxf(fmaf(sa[c], m, sc[c]), 0.f);
  }
}

// ---------------- layer 2 phase A: binary conv + stats ----------------
__global__ __launch_bounds__(256) void conv2_stats(
    const float* __restrict__ h1, const float* __restrict__ w2b,
    const float* __restrict__ b2, double* __restrict__ sums) {
  __shared__ float simg[8 * 1176];
  __shared__ float swt[2400];
  __shared__ float red[32];
  int tid = threadIdx.x;
  int img0 = blockIdx.x * 8;
  for (int i = tid; i < 8 * 1176; i += 256) simg[i] = h1[img0 * 1176 + i];
  for (int i = tid; i < 2400; i += 256) swt[i] = w2b[i];
  if (tid < 32) red[tid] = 0.f;
  __syncthreads();
  for (int c = 0; c < 16; ++c) {
    float bb = b2[c];
    float acc[4];
#pragma unroll
    for (int t = 0; t < 4; ++t) acc[t] = bb;
    for (int ci = 0; ci < 6; ++ci) {
      float wr[25];
#pragma unroll
      for (int k = 0; k < 25; ++k) wr[k] = swt[c * 150 + ci * 25 + k];
#pragma unroll
      for (int t = 0; t < 4; ++t) {
        int ip = tid + t * 256;
        if (ip < 800) {
          int img = ip / 100;
          int p = ip - img * 100;
          int oy = p / 10, ox = p - oy * 10;
          const float* base = &simg[img * 1176 + ci * 196 + oy * 14 + ox];
          float a = 0.f;
#pragma unroll
          for (int ky = 0; ky < 5; ++ky)
#pragma unroll
            for (int kx = 0; kx < 5; ++kx)
              a = fmaf(base[ky * 14 + kx], wr[ky * 5 + kx], a);
          acc[t] += a;
        }
      }
    }
    float s = 0.f, s2 = 0.f;
#pragma unroll
    for (int t = 0; t < 4; ++t) {
      int ip = tid + t * 256;
      if (ip < 800) {
        s += acc[t];
        s2 += acc[t] * acc[t];
      }
    }
    s = wave_sum(s);
    s2 = wave_sum(s2);
    if ((tid & 63) == 0) {
      atomicAdd(&red[c], s);
      atomicAdd(&red[16 + c], s2);
    }
  }
  __syncthreads();
  if (tid < 16) {
    int slot = blockIdx.x & 63;
    atomicAdd(&sums[SUM2 + tid * 64 + slot], (double)red[tid]);
    atomicAdd(&sums[SQ2 + tid * 64 + slot], (double)red[16 + tid]);
  }
}

// ---------------- layer 2 phase B: conv(recompute) + BN + relu + maxpool ----
__global__ __launch_bounds__(256) void conv2_pool(
    const float* __restrict__ h1, const float* __restrict__ w2b,
    const float* __restrict__ b2, const float* __restrict__ scales,
    float* __restrict__ h2) {
  __shared__ float simg[8 * 1176];
  __shared__ float swt[2400];
  __shared__ float sa[16], sc[16], sb[16];
  int tid = threadIdx.x;
  int img0 = blockIdx.x * 8;
  for (int i = tid; i < 8 * 1176; i += 256) simg[i] = h1[img0 * 1176 + i];
  for (int i = tid; i < 2400; i += 256) swt[i] = w2b[i];
  if (tid < 16) {
    sa[tid] = scales[A2 + tid];
    sc[tid] = scales[C2 + tid];
    sb[tid] = b2[tid];
  }
  __syncthreads();
  for (int idx = tid; idx < 8 * 400; idx += 256) {
    int img = idx / 400;
    int r = idx - img * 400;
    int c = r / 25;
    int p = r - c * 25;
    int py = p / 5, px = p - py * 5;
    int iy = py * 2, ix = px * 2;
    float m0, m1, m2, m3;
    m0 = m1 = m2 = m3 = sb[c];
    for (int ci = 0; ci < 6; ++ci) {
      const float* base = &simg[img * 1176 + ci * 196 + iy * 14 + ix];
      float win[36];
#pragma unroll
      for (int r6 = 0; r6 < 6; ++r6)
#pragma unroll
        for (int c6 = 0; c6 < 6; ++c6) win[r6 * 6 + c6] = base[r6 * 14 + c6];
#pragma unroll
      for (int ky = 0; ky < 5; ++ky)
#pragma unroll
        for (int kx = 0; kx < 5; ++kx) {
          float wv = swt[c * 150 + ci * 25 + ky * 5 + kx];
          m0 = fmaf(win[ky * 6 + kx], wv, m0);
          m1 = fmaf(win[ky * 6 + kx + 1], wv, m1);
          m2 = fmaf(win[(ky + 1) * 6 + kx], wv, m2);
          m3 = fmaf(win[(ky + 1) * 6 + kx + 1], wv, m3);
        }
    }
    float m = fmaxf(fmaxf(m0, m1), fmaxf(m2, m3));
    h2[(img0 + img) * 400 + r] = fmaxf(fmaf(sa[c], m, sc[c]), 0.f);
  }
}

// ---------------- layer 3: full dot (matmul) + stats ----------------
__global__ __launch_bounds__(256) void conv3_stats(
    const float* __restrict__ h2, const float* __restrict__ w3bT,
    const float* __restrict__ b3, float* __restrict__ y3,
    double* __restrict__ sums) {
  __shared__ float reds[120], redq[120];
  int tid = threadIdx.x;
  for (int i = tid; i < 120; i += 256) {
    reds[i] = 0.f;
    redq[i] = 0.f;
  }
  __syncthreads();
  int idx = blockIdx.x * 256 + tid;  // grid exactly covers 983040
  int img = idx / 120;
  int c = idx - img * 120;
  float acc = b3[c];
  const float* hp = h2 + img * 400;
  const float* wp = w3bT + c;
#pragma unroll 4
  for (int j = 0; j < 400; ++j) acc = fmaf(hp[j], wp[j * 120], acc);
  y3[idx] = acc;
  atomicAdd(&reds[c], acc);
  atomicAdd(&redq[c], acc * acc);
  __syncthreads();
  if (tid < 120) {
    int slot = blockIdx.x & 63;
    atomicAdd(&sums[SUM3 + tid * 64 + slot], (double)reds[tid]);
    atomicAdd(&sums[SQ3 + tid * 64 + slot], (double)redq[tid]);
  }
}

// ---------------- layer 3 BN + relu (in place) ----------------
__global__ __launch_bounds__(256) void bn3_relu(float* __restrict__ y3,
                                                const float* __restrict__ scales) {
  int idx = blockIdx.x * 256 + threadIdx.x;
  int c = idx % 120;
  y3[idx] = fmaxf(fmaf(scales[A3 + c], y3[idx], scales[C3 + c]), 0.f);
}

// ---------------- fc1(binary)+relu -> fc2 fused ----------------
__global__ __launch_bounds__(256) void fc_fused(
    const float* __restrict__ h3, const float* __restrict__ f1b,
    const float* __restrict__ b1, const float* __restrict__ w2,
    const float* __restrict__ b2, float* __restrict__ out) {
  __shared__ float sh3[32 * 121];
  __shared__ float sh4[32 * 85];
  __shared__ float sw2[10 * 85];
  __shared__ float sb1[84];
  __shared__ float sb2[10];
  int tid = threadIdx.x;
  int img0 = blockIdx.x * 32;
  for (int i = tid; i < 32 * 120; i += 256) {
    int s = i / 120, k = i - s * 120;
    sh3[s * 121 + k] = h3[img0 * 120 + i];
  }
  for (int i = tid; i < 840; i += 256) {
    int o = i / 84, k = i - o * 84;
    sw2[o * 85 + k] = w2[i];
  }
  if (tid < 84) sb1[tid] = b1[tid];
  if (tid < 10) sb2[tid] = b2[tid];
  __syncthreads();
  for (int idx = tid; idx < 32 * 84; idx += 256) {
    int s = idx / 84, j = idx - s * 84;
    float acc = sb1[j];
    const float* wp = f1b + j * 120;  // binarized fc1 weights from global (L2)
    const float* hp = &sh3[s * 121];
#pragma unroll 4
    for (int k = 0; k < 120; ++k) acc = fmaf(hp[k], wp[k], acc);
    sh4[s * 85 + j] = fmaxf(acc, 0.f);
  }
  __syncthreads();
  for (int idx = tid; idx < 320; idx += 256) {
    int s = idx / 10, o = idx - s * 10;
    float acc = sb2[o];
    const float* hp = &sh4[s * 85];
    const float* wp = &sw2[o * 85];
#pragma unroll 4
    for (int k = 0; k < 84; ++k) acc = fmaf(hp[k], wp[k], acc);
    out[(img0 + s) * 10 + o] = acc;
  }
}

extern "C" void kernel_launch(void* const* d_in, const int* in_sizes, int n_in,
                              void* d_out, int out_size, void* d_ws,
                              size_t ws_size, hipStream_t stream) {
  const float* x = (const float*)d_in[0];
  const float* conv1_w = (const float*)d_in[1];
  const float* conv1_b = (const float*)d_in[2];
  const float* conv2_w = (const float*)d_in[3];
  const float* conv2_b = (const float*)d_in[4];
  const float* bn2_g = (const float*)d_in[5];
  const float* bn2_b = (const float*)d_in[6];
  const float* conv3_w = (const float*)d_in[7];
  const float* conv3_b = (const float*)d_in[8];
  const float* bn3_g = (const float*)d_in[9];
  const float* bn3_b = (const float*)d_in[10];
  const float* fc1_w = (const float*)d_in[11];
  const float* fc1_b = (const float*)d_in[12];
  const float* fc2_w = (const float*)d_in[13];
  const float* fc2_b = (const float*)d_in[14];
  float* out = (float*)d_out;

  double* sums = (double*)d_ws;
  float* fbase = (float*)((char*)d_ws + DBL_BYTES);
  float* scales = fbase;
  float* w2b = fbase + W2B_OFF;
  float* w3bT = fbase + W3BT_OFF;
  float* f1b = fbase + FC1B_OFF;
  float* h1 = fbase + H1_OFF;
  float* h2 = fbase + H2_OFF;
  float* y3 = fbase + Y3_OFF;

  hipMemsetAsync(d_ws, 0, DBL_BYTES, stream);
  binarize_k<<<188, 256, 0, stream>>>(conv2_w, conv3_w, fc1_w, w2b, w3bT, f1b);

  conv1_stats<<<1024, 256, 0, stream>>>(x, conv1_w, conv1_b, sums);
  finalize_bn<<<1, 128, 0, stream>>>(sums + SUM1, sums + SQ1, 6,
                                     1.0 / (8192.0 * 784.0), 1e-4, nullptr,
                                     nullptr, scales + A1, scales + C1);
  conv1_pool<<<1024, 256, 0, stream>>>(x, conv1_w, conv1_b, scales, h1);

  conv2_stats<<<1024, 256, 0, stream>>>(h1, w2b, conv2_b, sums);
  finalize_bn<<<1, 128, 0, stream>>>(sums + SUM2, sums + SQ2, 16,
                                     1.0 / (8192.0 * 100.0), 1e-4, bn2_g, bn2_b,
                                     scales + A2, scales + C2);
  conv2_pool<<<1024, 256, 0, stream>>>(h1, w2b, conv2_b, scales, h2);

  conv3_stats<<<3840, 256, 0, stream>>>(h2, w3bT, conv3_b, y3, sums);
  finalize_bn<<<1, 128, 0, stream>>>(sums + SUM3, sums + SQ3, 120,
                                     1.0 / 8192.0, 1e-5, bn3_g, bn3_b,
                                     scales + A3, scales + C3);
  bn3_relu<<<3840, 256, 0, stream>>>(y3, scales);

  fc_fused<<<256, 256, 0, stream>>>(y3, f1b, fc1_b, fc2_w, fc2_b, out);
}

// Round 2
// 389.338 us; speedup vs baseline: 2.1552x; 2.1552x over previous
//
#include <hip/hip_runtime.h>

#define DEVFN __device__ __forceinline__

DEVFN float sgnf(float x) { return (x > 0.f) ? 1.f : ((x < 0.f) ? -1.f : 0.f); }

// ---- workspace layout ----
// double region (BN stat accumulators, 64 contention slots per channel)
#define SUM1 0        // 6*64 doubles
#define SQ1  384
#define SUM2 768      // 16*64
#define SQ2  1792
#define SUM3 2816     // 120*64
#define SQ3  10496
#define DBL_BYTES 145408  // 18176 doubles

// float region offsets (in floats, from fbase = ws + DBL_BYTES)
#define A1 0
#define C1 8
#define A2 16
#define C2 32
#define A3 48
#define C3 168
#define W2B_OFF  512                    // 3072 (16x6x32 padded)
#define W3BT_OFF 3584                   // 48000, layout [400][120]
#define FC1B_OFF 51584                  // 10080
#define H1_OFF   65536                  // 8192*1176 (pooled pre-BN layer1)
#define H2_OFF   (H1_OFF + 8192*1176)   // 8192*400  (pooled pre-BN layer2, bn applied in place)
#define Y3_OFF   (H2_OFF + 8192*400)    // 8192*120  (pre-BN layer3)

// ---------------- binarize weights ----------------
__global__ __launch_bounds__(256) void binarize_k(
    const float* __restrict__ w2, const float* __restrict__ w3,
    const float* __restrict__ f1, float* __restrict__ w2bp,
    float* __restrict__ w3bT, float* __restrict__ f1b) {
  int i = blockIdx.x * 256 + threadIdx.x;
  if (i < 3072) {  // padded layout [(c*6+ci)*32 + k], k<25 valid else 0
    int c = i / 192, r = i - c * 192;
    int ci = r / 32, k = r - ci * 32;
    w2bp[i] = (k < 25) ? sgnf(w2[(c * 6 + ci) * 25 + k]) : 0.f;
  }
  if (i < 48000) {
    int c = i / 400, j = i - c * 400;
    w3bT[j * 120 + c] = sgnf(w3[i]);  // transpose for coalesced conv3 reads
  }
  if (i < 10080) f1b[i] = sgnf(f1[i]);
}

// ---------------- layer 1 fused: conv + stats + pre-BN maxpool ----------------
// thread-task = (img, ch, pool-row py): 2 output rows x 28 cols, pooled to 14.
__global__ __launch_bounds__(256) void conv1_fused(
    const float* __restrict__ x, const float* __restrict__ w1,
    const float* __restrict__ b1, float* __restrict__ m1,
    double* __restrict__ sums) {
  __shared__ float simg[8 * 1088];   // row stride 34 (bank-conflict pad)
  __shared__ float swtp[6 * 40];     // padded weights, stride 40
  __shared__ float red[6], redq[6];
  int tid = threadIdx.x;
  int img0 = blockIdx.x * 8;
  {
    const float2* xg = (const float2*)(x + (size_t)img0 * 1024);
    for (int i2 = tid; i2 < 4096; i2 += 256) {
      int img = i2 >> 9;
      int r = (i2 >> 4) & 31;
      int c2 = i2 & 15;
      *(float2*)&simg[img * 1088 + r * 34 + c2 * 2] = xg[i2];
    }
  }
  for (int i = tid; i < 240; i += 256) {
    int ch = i / 40, k = i - ch * 40;
    swtp[i] = (k < 25) ? w1[ch * 25 + k] : 0.f;
  }
  if (tid < 6) { red[tid] = 0.f; redq[tid] = 0.f; }
  __syncthreads();

  for (int idx = tid; idx < 672; idx += 256) {
    int img = idx / 84;
    int r = idx - img * 84;
    int ch = r / 14;
    int py = r - ch * 14;
    float wr[25];
    {
      const float4* wp = (const float4*)&swtp[ch * 40];
#pragma unroll
      for (int t = 0; t < 6; ++t) {
        float4 v = wp[t];
        wr[4 * t] = v.x; wr[4 * t + 1] = v.y; wr[4 * t + 2] = v.z; wr[4 * t + 3] = v.w;
      }
      wr[24] = swtp[ch * 40 + 24];
    }
    float bb = b1[ch];
    float acc0[28], acc1[28];
#pragma unroll
    for (int o = 0; o < 28; ++o) { acc0[o] = bb; acc1[o] = bb; }
#pragma unroll
    for (int d = 0; d < 6; ++d) {
      int row = 2 * py + d;
      float rb[32];
      const float2* rp = (const float2*)&simg[img * 1088 + row * 34];
#pragma unroll
      for (int t = 0; t < 16; ++t) { float2 v = rp[t]; rb[2 * t] = v.x; rb[2 * t + 1] = v.y; }
      if (d < 5) {
#pragma unroll
        for (int kx = 0; kx < 5; ++kx) {
          float w = wr[d * 5 + kx];
#pragma unroll
          for (int o = 0; o < 28; ++o) acc0[o] = fmaf(rb[o + kx], w, acc0[o]);
        }
      }
      if (d >= 1) {
#pragma unroll
        for (int kx = 0; kx < 5; ++kx) {
          float w = wr[(d - 1) * 5 + kx];
#pragma unroll
          for (int o = 0; o < 28; ++o) acc1[o] = fmaf(rb[o + kx], w, acc1[o]);
        }
      }
    }
    float s = 0.f, s2 = 0.f;
#pragma unroll
    for (int o = 0; o < 28; ++o) {
      s += acc0[o] + acc1[o];
      s2 = fmaf(acc0[o], acc0[o], s2);
      s2 = fmaf(acc1[o], acc1[o], s2);
    }
    atomicAdd(&red[ch], s);
    atomicAdd(&redq[ch], s2);
    float* mp = m1 + (size_t)(img0 + img) * 1176 + ch * 196 + py * 14;
#pragma unroll
    for (int j = 0; j < 7; ++j) {
      float2 v;
      v.x = fmaxf(fmaxf(acc0[4 * j], acc0[4 * j + 1]), fmaxf(acc1[4 * j], acc1[4 * j + 1]));
      v.y = fmaxf(fmaxf(acc0[4 * j + 2], acc0[4 * j + 3]), fmaxf(acc1[4 * j + 2], acc1[4 * j + 3]));
      *(float2*)&mp[2 * j] = v;
    }
  }
  __syncthreads();
  if (tid < 6) {
    int slot = blockIdx.x & 63;
    atomicAdd(&sums[SUM1 + tid * 64 + slot], (double)red[tid]);
    atomicAdd(&sums[SQ1 + tid * 64 + slot], (double)redq[tid]);
  }
}

// ---------------- BN finalize: a = g*rsqrt(var+eps), c = beta - mean*a ------
__global__ __launch_bounds__(128) void finalize_bn(
    const double* __restrict__ sum, const double* __restrict__ sq, int nch,
    double invN, double eps, const float* __restrict__ gamma,
    const float* __restrict__ beta, float* __restrict__ a,
    float* __restrict__ c) {
  int ch = threadIdx.x;
  if (ch >= nch) return;
  double s = 0.0, q = 0.0;
  for (int k = 0; k < 64; ++k) {
    s += sum[ch * 64 + k];
    q += sq[ch * 64 + k];
  }
  double mean = s * invN;
  double var = q * invN - mean * mean;
  float inv = (float)(1.0 / sqrt(var + eps));
  float g = gamma ? fmaxf(gamma[ch], 0.01f) : 1.f;
  float av = g * inv;
  float cv = (beta ? beta[ch] : 0.f) - (float)mean * av;
  a[ch] = av;
  c[ch] = cv;
}

// ---------------- layer 2 fused: BN1+relu on load, conv + stats + pre-BN pool
// block = 320 threads; task = (chpair cp, py, img): 2ch x 2rows x 10 cols -> 2x5 pooled
__global__ __launch_bounds__(320) void conv2_fused(
    const float* __restrict__ m1, const float* __restrict__ w2bp,
    const float* __restrict__ b2, const float* __restrict__ scales,
    float* __restrict__ m2, double* __restrict__ sums) {
  __shared__ float sh1[8 * 1176];
  __shared__ float swt[3072];
  __shared__ float sa1[6], sc1[6];
  __shared__ float red[16], redq[16];
  int tid = threadIdx.x;
  int img0 = blockIdx.x * 8;
  if (tid < 6) { sa1[tid] = scales[A1 + tid]; sc1[tid] = scales[C1 + tid]; }
  if (tid < 16) { red[tid] = 0.f; redq[tid] = 0.f; }
  __syncthreads();
  {
    const float4* mg = (const float4*)(m1 + (size_t)img0 * 1176);
    float4* s4 = (float4*)sh1;
    for (int i4 = tid; i4 < 2352; i4 += 320) {
      int ch = (i4 % 294) / 49;  // 49 float4 per (ch,row-block) of 196
      float a = sa1[ch], c = sc1[ch];
      float4 v = mg[i4];
      v.x = fmaxf(fmaf(a, v.x, c), 0.f);
      v.y = fmaxf(fmaf(a, v.y, c), 0.f);
      v.z = fmaxf(fmaf(a, v.z, c), 0.f);
      v.w = fmaxf(fmaf(a, v.w, c), 0.f);
      s4[i4] = v;
    }
    const float4* wg = (const float4*)w2bp;
    float4* w4 = (float4*)swt;
    for (int i4 = tid; i4 < 768; i4 += 320) w4[i4] = wg[i4];
  }
  __syncthreads();

  // task decode: img fastest so waves share the channel-pair (weight broadcast)
  int cp = tid / 40;
  int r = tid - cp * 40;
  int py = r >> 3;
  int img = r & 7;
  int ch0 = cp * 2, ch1 = ch0 + 1;
  float acc[2][2][10];
  float b0 = b2[ch0], b1v = b2[ch1];
#pragma unroll
  for (int o = 0; o < 10; ++o) {
    acc[0][0][o] = b0; acc[0][1][o] = b0;
    acc[1][0][o] = b1v; acc[1][1][o] = b1v;
  }
  for (int ci = 0; ci < 6; ++ci) {
    float w0[25], w1r[25];
    {
      const float4* p0 = (const float4*)&swt[(ch0 * 6 + ci) * 32];
      const float4* p1 = (const float4*)&swt[(ch1 * 6 + ci) * 32];
#pragma unroll
      for (int t = 0; t < 6; ++t) {
        float4 a = p0[t], b = p1[t];
        w0[4 * t] = a.x; w0[4 * t + 1] = a.y; w0[4 * t + 2] = a.z; w0[4 * t + 3] = a.w;
        w1r[4 * t] = b.x; w1r[4 * t + 1] = b.y; w1r[4 * t + 2] = b.z; w1r[4 * t + 3] = b.w;
      }
      w0[24] = swt[(ch0 * 6 + ci) * 32 + 24];
      w1r[24] = swt[(ch1 * 6 + ci) * 32 + 24];
    }
    const float* base = &sh1[img * 1176 + ci * 196 + 28 * py];
#pragma unroll
    for (int d = 0; d < 6; ++d) {
      float rb[14];
      const float2* rp = (const float2*)(base + d * 14);
#pragma unroll
      for (int t = 0; t < 7; ++t) { float2 v = rp[t]; rb[2 * t] = v.x; rb[2 * t + 1] = v.y; }
      if (d < 5) {
#pragma unroll
        for (int kx = 0; kx < 5; ++kx) {
          float wa = w0[d * 5 + kx], wb = w1r[d * 5 + kx];
#pragma unroll
          for (int o = 0; o < 10; ++o) {
            acc[0][0][o] = fmaf(rb[o + kx], wa, acc[0][0][o]);
            acc[1][0][o] = fmaf(rb[o + kx], wb, acc[1][0][o]);
          }
        }
      }
      if (d >= 1) {
#pragma unroll
        for (int kx = 0; kx < 5; ++kx) {
          float wa = w0[(d - 1) * 5 + kx], wb = w1r[(d - 1) * 5 + kx];
#pragma unroll
          for (int o = 0; o < 10; ++o) {
            acc[0][1][o] = fmaf(rb[o + kx], wa, acc[0][1][o]);
            acc[1][1][o] = fmaf(rb[o + kx], wb, acc[1][1][o]);
          }
        }
      }
    }
  }
  float s0 = 0.f, q0 = 0.f, s1 = 0.f, q1 = 0.f;
#pragma unroll
  for (int rr = 0; rr < 2; ++rr)
#pragma unroll
    for (int o = 0; o < 10; ++o) {
      float v0 = acc[0][rr][o], v1 = acc[1][rr][o];
      s0 += v0; q0 = fmaf(v0, v0, q0);
      s1 += v1; q1 = fmaf(v1, v1, q1);
    }
  atomicAdd(&red[ch0], s0); atomicAdd(&redq[ch0], q0);
  atomicAdd(&red[ch1], s1); atomicAdd(&redq[ch1], q1);
  {
    float* mp0 = m2 + (size_t)(img0 + img) * 400 + ch0 * 25 + py * 5;
    float* mp1 = m2 + (size_t)(img0 + img) * 400 + ch1 * 25 + py * 5;
#pragma unroll
    for (int i = 0; i < 5; ++i) {
      mp0[i] = fmaxf(fmaxf(acc[0][0][2 * i], acc[0][0][2 * i + 1]),
                     fmaxf(acc[0][1][2 * i], acc[0][1][2 * i + 1]));
      mp1[i] = fmaxf(fmaxf(acc[1][0][2 * i], acc[1][0][2 * i + 1]),
                     fmaxf(acc[1][1][2 * i], acc[1][1][2 * i + 1]));
    }
  }
  __syncthreads();
  if (tid < 16) {
    int slot = blockIdx.x & 63;
    atomicAdd(&sums[SUM2 + tid * 64 + slot], (double)red[tid]);
    atomicAdd(&sums[SQ2 + tid * 64 + slot], (double)redq[tid]);
  }
}

// ---------------- BN2 + relu, in place on m2 ----------------
__global__ __launch_bounds__(256) void bn2_relu(float* __restrict__ m2,
                                                const float* __restrict__ scales) {
  int idx = blockIdx.x * 256 + threadIdx.x;  // 3276800 exact
  int c = (idx % 400) / 25;
  m2[idx] = fmaxf(fmaf(scales[A2 + c], m2[idx], scales[C2 + c]), 0.f);
}

// ---------------- layer 3: full dot (matmul) + stats ----------------
__global__ __launch_bounds__(256) void conv3_stats(
    const float* __restrict__ h2, const float* __restrict__ w3bT,
    const float* __restrict__ b3, float* __restrict__ y3,
    double* __restrict__ sums) {
  __shared__ float reds[120], redq[120];
  int tid = threadIdx.x;
  for (int i = tid; i < 120; i += 256) {
    reds[i] = 0.f;
    redq[i] = 0.f;
  }
  __syncthreads();
  int idx = blockIdx.x * 256 + tid;  // grid exactly covers 983040
  int img = idx / 120;
  int c = idx - img * 120;
  float acc = b3[c];
  const float* hp = h2 + (size_t)img * 400;
  const float* wp = w3bT + c;
#pragma unroll 4
  for (int j = 0; j < 400; ++j) acc = fmaf(hp[j], wp[j * 120], acc);
  y3[idx] = acc;
  atomicAdd(&reds[c], acc);
  atomicAdd(&redq[c], acc * acc);
  __syncthreads();
  if (tid < 120) {
    int slot = blockIdx.x & 63;
    atomicAdd(&sums[SUM3 + tid * 64 + slot], (double)reds[tid]);
    atomicAdd(&sums[SQ3 + tid * 64 + slot], (double)redq[tid]);
  }
}

// ---------------- fc1(binary)+relu -> fc2 fused, BN3+relu on load ----------
__global__ __launch_bounds__(256) void fc_fused(
    const float* __restrict__ y3, const float* __restrict__ scales,
    const float* __restrict__ f1b, const float* __restrict__ b1,
    const float* __restrict__ w2, const float* __restrict__ b2,
    float* __restrict__ out) {
  __shared__ float sh3[32 * 121];
  __shared__ float sh4[32 * 85];
  __shared__ float sw2[10 * 85];
  __shared__ float sa3[120], sc3[120];
  __shared__ float sb1[84], sb2[10];
  int tid = threadIdx.x;
  int img0 = blockIdx.x * 32;
  if (tid < 120) { sa3[tid] = scales[A3 + tid]; sc3[tid] = scales[C3 + tid]; }
  if (tid >= 128 && tid < 212) sb1[tid - 128] = b1[tid - 128];
  if (tid >= 216 && tid < 226) sb2[tid - 216] = b2[tid - 216];
  __syncthreads();
  for (int i = tid; i < 32 * 120; i += 256) {
    int s = i / 120, k = i - s * 120;
    sh3[s * 121 + k] = fmaxf(fmaf(sa3[k], y3[(size_t)img0 * 120 + i], sc3[k]), 0.f);
  }
  for (int i = tid; i < 840; i += 256) {
    int o = i / 84, k = i - o * 84;
    sw2[o * 85 + k] = w2[i];
  }
  __syncthreads();
  for (int idx = tid; idx < 32 * 84; idx += 256) {
    int s = idx / 84, j = idx - s * 84;
    float acc = sb1[j];
    const float* wp = f1b + j * 120;
    const float* hp = &sh3[s * 121];
#pragma unroll 4
    for (int k = 0; k < 120; ++k) acc = fmaf(hp[k], wp[k], acc);
    sh4[s * 85 + j] = fmaxf(acc, 0.f);
  }
  __syncthreads();
  for (int idx = tid; idx < 320; idx += 256) {
    int s = idx / 10, o = idx - s * 10;
    float acc = sb2[o];
    const float* hp = &sh4[s * 85];
    const float* wp = &sw2[o * 85];
#pragma unroll 4
    for (int k = 0; k < 84; ++k) acc = fmaf(hp[k], wp[k], acc);
    out[(img0 + s) * 10 + o] = acc;
  }
}

extern "C" void kernel_launch(void* const* d_in, const int* in_sizes, int n_in,
                              void* d_out, int out_size, void* d_ws,
                              size_t ws_size, hipStream_t stream) {
  const float* x = (const float*)d_in[0];
  const float* conv1_w = (const float*)d_in[1];
  const float* conv1_b = (const float*)d_in[2];
  const float* conv2_w = (const float*)d_in[3];
  const float* conv2_b = (const float*)d_in[4];
  const float* bn2_g = (const float*)d_in[5];
  const float* bn2_b = (const float*)d_in[6];
  const float* conv3_w = (const float*)d_in[7];
  const float* conv3_b = (const float*)d_in[8];
  const float* bn3_g = (const float*)d_in[9];
  const float* bn3_b = (const float*)d_in[10];
  const float* fc1_w = (const float*)d_in[11];
  const float* fc1_b = (const float*)d_in[12];
  const float* fc2_w = (const float*)d_in[13];
  const float* fc2_b = (const float*)d_in[14];
  float* out = (float*)d_out;

  double* sums = (double*)d_ws;
  float* fbase = (float*)((char*)d_ws + DBL_BYTES);
  float* scales = fbase;
  float* w2bp = fbase + W2B_OFF;
  float* w3bT = fbase + W3BT_OFF;
  float* f1b = fbase + FC1B_OFF;
  float* m1 = fbase + H1_OFF;
  float* m2 = fbase + H2_OFF;
  float* y3 = fbase + Y3_OFF;

  hipMemsetAsync(d_ws, 0, DBL_BYTES, stream);
  binarize_k<<<188, 256, 0, stream>>>(conv2_w, conv3_w, fc1_w, w2bp, w3bT, f1b);

  conv1_fused<<<1024, 256, 0, stream>>>(x, conv1_w, conv1_b, m1, sums);
  finalize_bn<<<1, 128, 0, stream>>>(sums + SUM1, sums + SQ1, 6,
                                     1.0 / (8192.0 * 784.0), 1e-4, nullptr,
                                     nullptr, scales + A1, scales + C1);

  conv2_fused<<<1024, 320, 0, stream>>>(m1, w2bp, conv2_b, scales, m2, sums);
  finalize_bn<<<1, 128, 0, stream>>>(sums + SUM2, sums + SQ2, 16,
                                     1.0 / (8192.0 * 100.0), 1e-4, bn2_g, bn2_b,
                                     scales + A2, scales + C2);
  bn2_relu<<<12800, 256, 0, stream>>>(m2, scales);

  conv3_stats<<<3840, 256, 0, stream>>>(m2, w3bT, conv3_b, y3, sums);
  finalize_bn<<<1, 128, 0, stream>>>(sums + SUM3, sums + SQ3, 120,
                                     1.0 / 8192.0, 1e-5, bn3_g, bn3_b,
                                     scales + A3, scales + C3);

  fc_fused<<<256, 256, 0, stream>>>(y3, scales, f1b, fc1_b, fc2_w, fc2_b, out);
}

// Round 3
// 311.182 us; speedup vs baseline: 2.6965x; 1.2512x over previous
//
#include <hip/hip_runtime.h>

#define DEVFN __device__ __forceinline__

DEVFN float sgnf(float x) { return (x > 0.f) ? 1.f : ((x < 0.f) ? -1.f : 0.f); }

// ---- workspace layout ----
// double region (BN stat accumulators, 64 contention slots per channel)
#define SUM1 0        // 6*64 doubles
#define SQ1  384
#define SUM2 768      // 16*64
#define SQ2  1792
#define SUM3 2816     // 120*64
#define SQ3  10496
#define DBL_BYTES 145408  // 18176 doubles

// float region offsets (in floats, from fbase = ws + DBL_BYTES)
#define A1 0
#define C1 8
#define A2 16
#define C2 32
#define A3 48
#define C3 168
#define W2B_OFF  512                    // 3072 (16x6x32 padded)
#define W3BT_OFF 3584                   // 48000, layout [400][120]
#define FC1B_OFF 51584                  // 10080
#define H1_OFF   65536                  // 8192*1176 (pooled pre-BN layer1)
#define H2_OFF   (H1_OFF + 8192*1176)   // 8192*400  (pooled pre-BN layer2; BN2 applied on load in conv3)
#define Y3_OFF   (H2_OFF + 8192*400)    // 8192*120  (pre-BN layer3)

// ---------------- binarize weights ----------------
__global__ __launch_bounds__(256) void binarize_k(
    const float* __restrict__ w2, const float* __restrict__ w3,
    const float* __restrict__ f1, float* __restrict__ w2bp,
    float* __restrict__ w3bT, float* __restrict__ f1b) {
  int i = blockIdx.x * 256 + threadIdx.x;
  if (i < 3072) {  // padded layout [(c*6+ci)*32 + k], k<25 valid else 0
    int c = i / 192, r = i - c * 192;
    int ci = r / 32, k = r - ci * 32;
    w2bp[i] = (k < 25) ? sgnf(w2[(c * 6 + ci) * 25 + k]) : 0.f;
  }
  if (i < 48000) {
    int c = i / 400, j = i - c * 400;
    w3bT[j * 120 + c] = sgnf(w3[i]);  // transpose for coalesced conv3 reads
  }
  if (i < 10080) f1b[i] = sgnf(f1[i]);
}

// ---------------- layer 1 fused: conv + stats + pre-BN maxpool ----------------
// thread-task = (img, ch, pool-row py): 2 output rows x 28 cols, pooled to 14.
__global__ __launch_bounds__(256) void conv1_fused(
    const float* __restrict__ x, const float* __restrict__ w1,
    const float* __restrict__ b1, float* __restrict__ m1,
    double* __restrict__ sums) {
  __shared__ float simg[8 * 1088];   // row stride 34 (bank-conflict pad)
  __shared__ float swtp[6 * 40];     // padded weights, stride 40
  __shared__ float red[6], redq[6];
  int tid = threadIdx.x;
  int img0 = blockIdx.x * 8;
  {
    const float2* xg = (const float2*)(x + (size_t)img0 * 1024);
    for (int i2 = tid; i2 < 4096; i2 += 256) {
      int img = i2 >> 9;
      int r = (i2 >> 4) & 31;
      int c2 = i2 & 15;
      *(float2*)&simg[img * 1088 + r * 34 + c2 * 2] = xg[i2];
    }
  }
  for (int i = tid; i < 240; i += 256) {
    int ch = i / 40, k = i - ch * 40;
    swtp[i] = (k < 25) ? w1[ch * 25 + k] : 0.f;
  }
  if (tid < 6) { red[tid] = 0.f; redq[tid] = 0.f; }
  __syncthreads();

  for (int idx = tid; idx < 672; idx += 256) {
    int img = idx / 84;
    int r = idx - img * 84;
    int ch = r / 14;
    int py = r - ch * 14;
    float wr[25];
    {
      const float4* wp = (const float4*)&swtp[ch * 40];
#pragma unroll
      for (int t = 0; t < 6; ++t) {
        float4 v = wp[t];
        wr[4 * t] = v.x; wr[4 * t + 1] = v.y; wr[4 * t + 2] = v.z; wr[4 * t + 3] = v.w;
      }
      wr[24] = swtp[ch * 40 + 24];
    }
    float bb = b1[ch];
    float acc0[28], acc1[28];
#pragma unroll
    for (int o = 0; o < 28; ++o) { acc0[o] = bb; acc1[o] = bb; }
#pragma unroll
    for (int d = 0; d < 6; ++d) {
      int row = 2 * py + d;
      float rb[32];
      const float2* rp = (const float2*)&simg[img * 1088 + row * 34];
#pragma unroll
      for (int t = 0; t < 16; ++t) { float2 v = rp[t]; rb[2 * t] = v.x; rb[2 * t + 1] = v.y; }
      if (d < 5) {
#pragma unroll
        for (int kx = 0; kx < 5; ++kx) {
          float w = wr[d * 5 + kx];
#pragma unroll
          for (int o = 0; o < 28; ++o) acc0[o] = fmaf(rb[o + kx], w, acc0[o]);
        }
      }
      if (d >= 1) {
#pragma unroll
        for (int kx = 0; kx < 5; ++kx) {
          float w = wr[(d - 1) * 5 + kx];
#pragma unroll
          for (int o = 0; o < 28; ++o) acc1[o] = fmaf(rb[o + kx], w, acc1[o]);
        }
      }
    }
    float s = 0.f, s2 = 0.f;
#pragma unroll
    for (int o = 0; o < 28; ++o) {
      s += acc0[o] + acc1[o];
      s2 = fmaf(acc0[o], acc0[o], s2);
      s2 = fmaf(acc1[o], acc1[o], s2);
    }
    atomicAdd(&red[ch], s);
    atomicAdd(&redq[ch], s2);
    float* mp = m1 + (size_t)(img0 + img) * 1176 + ch * 196 + py * 14;
#pragma unroll
    for (int j = 0; j < 7; ++j) {
      float2 v;
      v.x = fmaxf(fmaxf(acc0[4 * j], acc0[4 * j + 1]), fmaxf(acc1[4 * j], acc1[4 * j + 1]));
      v.y = fmaxf(fmaxf(acc0[4 * j + 2], acc0[4 * j + 3]), fmaxf(acc1[4 * j + 2], acc1[4 * j + 3]));
      *(float2*)&mp[2 * j] = v;
    }
  }
  __syncthreads();
  if (tid < 6) {
    int slot = blockIdx.x & 63;
    atomicAdd(&sums[SUM1 + tid * 64 + slot], (double)red[tid]);
    atomicAdd(&sums[SQ1 + tid * 64 + slot], (double)redq[tid]);
  }
}

// ---------------- BN finalize: a = g*rsqrt(var+eps), c = beta - mean*a ------
__global__ __launch_bounds__(128) void finalize_bn(
    const double* __restrict__ sum, const double* __restrict__ sq, int nch,
    double invN, double eps, const float* __restrict__ gamma,
    const float* __restrict__ beta, float* __restrict__ a,
    float* __restrict__ c) {
  int ch = threadIdx.x;
  if (ch >= nch) return;
  double s = 0.0, q = 0.0;
  for (int k = 0; k < 64; ++k) {
    s += sum[ch * 64 + k];
    q += sq[ch * 64 + k];
  }
  double mean = s * invN;
  double var = q * invN - mean * mean;
  float inv = (float)(1.0 / sqrt(var + eps));
  float g = gamma ? fmaxf(gamma[ch], 0.01f) : 1.f;
  float av = g * inv;
  float cv = (beta ? beta[ch] : 0.f) - (float)mean * av;
  a[ch] = av;
  c[ch] = cv;
}

// ---------------- layer 2 fused: BN1+relu on load, conv + stats + pre-BN pool
// block = 320 threads; task = (chpair cp, py, img): 2ch x 2rows x 10 cols -> 2x5 pooled
__global__ __launch_bounds__(320) void conv2_fused(
    const float* __restrict__ m1, const float* __restrict__ w2bp,
    const float* __restrict__ b2, const float* __restrict__ scales,
    float* __restrict__ m2, double* __restrict__ sums) {
  __shared__ float sh1[8 * 1176];
  __shared__ float swt[3072];
  __shared__ float sa1[6], sc1[6];
  __shared__ float red[16], redq[16];
  int tid = threadIdx.x;
  int img0 = blockIdx.x * 8;
  if (tid < 6) { sa1[tid] = scales[A1 + tid]; sc1[tid] = scales[C1 + tid]; }
  if (tid < 16) { red[tid] = 0.f; redq[tid] = 0.f; }
  __syncthreads();
  {
    const float4* mg = (const float4*)(m1 + (size_t)img0 * 1176);
    float4* s4 = (float4*)sh1;
    for (int i4 = tid; i4 < 2352; i4 += 320) {
      int ch = (i4 % 294) / 49;  // 49 float4 per (ch,row-block) of 196
      float a = sa1[ch], c = sc1[ch];
      float4 v = mg[i4];
      v.x = fmaxf(fmaf(a, v.x, c), 0.f);
      v.y = fmaxf(fmaf(a, v.y, c), 0.f);
      v.z = fmaxf(fmaf(a, v.z, c), 0.f);
      v.w = fmaxf(fmaf(a, v.w, c), 0.f);
      s4[i4] = v;
    }
    const float4* wg = (const float4*)w2bp;
    float4* w4 = (float4*)swt;
    for (int i4 = tid; i4 < 768; i4 += 320) w4[i4] = wg[i4];
  }
  __syncthreads();

  // task decode: img fastest so waves share the channel-pair (weight broadcast)
  int cp = tid / 40;
  int r = tid - cp * 40;
  int py = r >> 3;
  int img = r & 7;
  int ch0 = cp * 2, ch1 = ch0 + 1;
  float acc[2][2][10];
  float b0 = b2[ch0], b1v = b2[ch1];
#pragma unroll
  for (int o = 0; o < 10; ++o) {
    acc[0][0][o] = b0; acc[0][1][o] = b0;
    acc[1][0][o] = b1v; acc[1][1][o] = b1v;
  }
  for (int ci = 0; ci < 6; ++ci) {
    float w0[25], w1r[25];
    {
      const float4* p0 = (const float4*)&swt[(ch0 * 6 + ci) * 32];
      const float4* p1 = (const float4*)&swt[(ch1 * 6 + ci) * 32];
#pragma unroll
      for (int t = 0; t < 6; ++t) {
        float4 a = p0[t], b = p1[t];
        w0[4 * t] = a.x; w0[4 * t + 1] = a.y; w0[4 * t + 2] = a.z; w0[4 * t + 3] = a.w;
        w1r[4 * t] = b.x; w1r[4 * t + 1] = b.y; w1r[4 * t + 2] = b.z; w1r[4 * t + 3] = b.w;
      }
      w0[24] = swt[(ch0 * 6 + ci) * 32 + 24];
      w1r[24] = swt[(ch1 * 6 + ci) * 32 + 24];
    }
    const float* base = &sh1[img * 1176 + ci * 196 + 28 * py];
#pragma unroll
    for (int d = 0; d < 6; ++d) {
      float rb[14];
      const float2* rp = (const float2*)(base + d * 14);
#pragma unroll
      for (int t = 0; t < 7; ++t) { float2 v = rp[t]; rb[2 * t] = v.x; rb[2 * t + 1] = v.y; }
      if (d < 5) {
#pragma unroll
        for (int kx = 0; kx < 5; ++kx) {
          float wa = w0[d * 5 + kx], wb = w1r[d * 5 + kx];
#pragma unroll
          for (int o = 0; o < 10; ++o) {
            acc[0][0][o] = fmaf(rb[o + kx], wa, acc[0][0][o]);
            acc[1][0][o] = fmaf(rb[o + kx], wb, acc[1][0][o]);
          }
        }
      }
      if (d >= 1) {
#pragma unroll
        for (int kx = 0; kx < 5; ++kx) {
          float wa = w0[(d - 1) * 5 + kx], wb = w1r[(d - 1) * 5 + kx];
#pragma unroll
          for (int o = 0; o < 10; ++o) {
            acc[0][1][o] = fmaf(rb[o + kx], wa, acc[0][1][o]);
            acc[1][1][o] = fmaf(rb[o + kx], wb, acc[1][1][o]);
          }
        }
      }
    }
  }
  float s0 = 0.f, q0 = 0.f, s1 = 0.f, q1 = 0.f;
#pragma unroll
  for (int rr = 0; rr < 2; ++rr)
#pragma unroll
    for (int o = 0; o < 10; ++o) {
      float v0 = acc[0][rr][o], v1 = acc[1][rr][o];
      s0 += v0; q0 = fmaf(v0, v0, q0);
      s1 += v1; q1 = fmaf(v1, v1, q1);
    }
  atomicAdd(&red[ch0], s0); atomicAdd(&redq[ch0], q0);
  atomicAdd(&red[ch1], s1); atomicAdd(&redq[ch1], q1);
  {
    float* mp0 = m2 + (size_t)(img0 + img) * 400 + ch0 * 25 + py * 5;
    float* mp1 = m2 + (size_t)(img0 + img) * 400 + ch1 * 25 + py * 5;
#pragma unroll
    for (int i = 0; i < 5; ++i) {
      mp0[i] = fmaxf(fmaxf(acc[0][0][2 * i], acc[0][0][2 * i + 1]),
                     fmaxf(acc[0][1][2 * i], acc[0][1][2 * i + 1]));
      mp1[i] = fmaxf(fmaxf(acc[1][0][2 * i], acc[1][0][2 * i + 1]),
                     fmaxf(acc[1][1][2 * i], acc[1][1][2 * i + 1]));
    }
  }
  __syncthreads();
  if (tid < 16) {
    int slot = blockIdx.x & 63;
    atomicAdd(&sums[SUM2 + tid * 64 + slot], (double)red[tid]);
    atomicAdd(&sums[SQ2 + tid * 64 + slot], (double)redq[tid]);
  }
}

// ---------------- layer 3: LDS-tiled GEMM, BN2+relu fused on A-load, + stats
// grid 256, block 256. M-tile=32 imgs, N=120 (pad 128), K=400 in 4 chunks.
// per-thread 4 imgs x 4 ch register tile. A stored k-major for b128 reads.
__global__ __launch_bounds__(256) void conv3_gemm(
    const float* __restrict__ m2, const float* __restrict__ w3bT,
    const float* __restrict__ b3, const float* __restrict__ scales,
    float* __restrict__ y3, double* __restrict__ sums) {
  __shared__ float sA[100 * 36];    // [k][img], img-dim padded 32->36
  __shared__ float sB[100 * 128];   // [k][ch], ch padded 120->128 (zeros)
  __shared__ float red[128], redq[128];
  __shared__ float sa2[16], sc2[16];
  int tid = threadIdx.x;
  int img0 = blockIdx.x * 32;
  if (tid < 128) { red[tid] = 0.f; redq[tid] = 0.f; }
  if (tid >= 128 && tid < 144) {
    sa2[tid - 128] = scales[A2 + tid - 128];
    sc2[tid - 128] = scales[C2 + tid - 128];
  }
  int tx = tid & 31, ty = tid >> 5;
  int c0 = tx * 4;
  float acc[4][4] = {};
  for (int kc = 0; kc < 400; kc += 100) {
    __syncthreads();  // also covers sa2/red init before first staging
    // stage A: 32 imgs x 100 k, transpose to k-major, BN2+relu applied
    for (int i4 = tid; i4 < 800; i4 += 256) {
      int i = i4 / 25, t = i4 - i * 25;
      float4 v = *(const float4*)(m2 + (size_t)(img0 + i) * 400 + kc + t * 4);
      int jj = t * 4;
      float vv[4] = {v.x, v.y, v.z, v.w};
#pragma unroll
      for (int e = 0; e < 4; ++e) {
        int ch = (kc + jj + e) / 25;
        sA[(jj + e) * 36 + i] = fmaxf(fmaf(sa2[ch], vv[e], sc2[ch]), 0.f);
      }
    }
    // stage B: 100 k x 120 ch (+8 zero pad)
    for (int i4 = tid; i4 < 3200; i4 += 256) {
      int j = i4 >> 5, c4 = i4 & 31;
      float4 v;
      if (c4 < 30)
        v = *(const float4*)(w3bT + (size_t)(kc + j) * 120 + c4 * 4);
      else
        v = make_float4(0.f, 0.f, 0.f, 0.f);
      *(float4*)(sB + j * 128 + c4 * 4) = v;
    }
    __syncthreads();
#pragma unroll 2
    for (int j = 0; j < 100; ++j) {
      float4 a = *(const float4*)(sA + j * 36 + ty * 4);
      float4 b = *(const float4*)(sB + j * 128 + c0);
      acc[0][0] = fmaf(a.x, b.x, acc[0][0]);
      acc[0][1] = fmaf(a.x, b.y, acc[0][1]);
      acc[0][2] = fmaf(a.x, b.z, acc[0][2]);
      acc[0][3] = fmaf(a.x, b.w, acc[0][3]);
      acc[1][0] = fmaf(a.y, b.x, acc[1][0]);
      acc[1][1] = fmaf(a.y, b.y, acc[1][1]);
      acc[1][2] = fmaf(a.y, b.z, acc[1][2]);
      acc[1][3] = fmaf(a.y, b.w, acc[1][3]);
      acc[2][0] = fmaf(a.z, b.x, acc[2][0]);
      acc[2][1] = fmaf(a.z, b.y, acc[2][1]);
      acc[2][2] = fmaf(a.z, b.z, acc[2][2]);
      acc[2][3] = fmaf(a.z, b.w, acc[2][3]);
      acc[3][0] = fmaf(a.w, b.x, acc[3][0]);
      acc[3][1] = fmaf(a.w, b.y, acc[3][1]);
      acc[3][2] = fmaf(a.w, b.z, acc[3][2]);
      acc[3][3] = fmaf(a.w, b.w, acc[3][3]);
    }
  }
  // epilogue: +bias, write y3, accumulate stats
  if (c0 < 120) {
    float4 bias = *(const float4*)(b3 + c0);
    float sc[4] = {0.f, 0.f, 0.f, 0.f}, sq[4] = {0.f, 0.f, 0.f, 0.f};
#pragma unroll
    for (int i = 0; i < 4; ++i) {
      float4 v;
      v.x = acc[i][0] + bias.x;
      v.y = acc[i][1] + bias.y;
      v.z = acc[i][2] + bias.z;
      v.w = acc[i][3] + bias.w;
      *(float4*)(y3 + (size_t)(img0 + ty * 4 + i) * 120 + c0) = v;
      sc[0] += v.x; sq[0] = fmaf(v.x, v.x, sq[0]);
      sc[1] += v.y; sq[1] = fmaf(v.y, v.y, sq[1]);
      sc[2] += v.z; sq[2] = fmaf(v.z, v.z, sq[2]);
      sc[3] += v.w; sq[3] = fmaf(v.w, v.w, sq[3]);
    }
#pragma unroll
    for (int c = 0; c < 4; ++c) {
      atomicAdd(&red[c0 + c], sc[c]);
      atomicAdd(&redq[c0 + c], sq[c]);
    }
  }
  __syncthreads();
  if (tid < 120) {
    int slot = blockIdx.x & 63;
    atomicAdd(&sums[SUM3 + tid * 64 + slot], (double)red[tid]);
    atomicAdd(&sums[SQ3 + tid * 64 + slot], (double)redq[tid]);
  }
}

// ---------------- fc1(binary)+relu -> fc2 fused, BN3+relu on load ----------
__global__ __launch_bounds__(256) void fc_fused(
    const float* __restrict__ y3, const float* __restrict__ scales,
    const float* __restrict__ f1b, const float* __restrict__ b1,
    const float* __restrict__ w2, const float* __restrict__ b2,
    float* __restrict__ out) {
  __shared__ float sh3[32 * 121];
  __shared__ float sh4[32 * 85];
  __shared__ float sw2[10 * 85];
  __shared__ float sa3[120], sc3[120];
  __shared__ float sb1[84], sb2[10];
  int tid = threadIdx.x;
  int img0 = blockIdx.x * 32;
  if (tid < 120) { sa3[tid] = scales[A3 + tid]; sc3[tid] = scales[C3 + tid]; }
  if (tid >= 128 && tid < 212) sb1[tid - 128] = b1[tid - 128];
  if (tid >= 216 && tid < 226) sb2[tid - 216] = b2[tid - 216];
  __syncthreads();
  for (int i = tid; i < 32 * 120; i += 256) {
    int s = i / 120, k = i - s * 120;
    sh3[s * 121 + k] = fmaxf(fmaf(sa3[k], y3[(size_t)img0 * 120 + i], sc3[k]), 0.f);
  }
  for (int i = tid; i < 840; i += 256) {
    int o = i / 84, k = i - o * 84;
    sw2[o * 85 + k] = w2[i];
  }
  __syncthreads();
  for (int idx = tid; idx < 32 * 84; idx += 256) {
    int s = idx / 84, j = idx - s * 84;
    float acc = sb1[j];
    const float* wp = f1b + j * 120;
    const float* hp = &sh3[s * 121];
#pragma unroll 4
    for (int k = 0; k < 120; ++k) acc = fmaf(hp[k], wp[k], acc);
    sh4[s * 85 + j] = fmaxf(acc, 0.f);
  }
  __syncthreads();
  for (int idx = tid; idx < 320; idx += 256) {
    int s = idx / 10, o = idx - s * 10;
    float acc = sb2[o];
    const float* hp = &sh4[s * 85];
    const float* wp = &sw2[o * 85];
#pragma unroll 4
    for (int k = 0; k < 84; ++k) acc = fmaf(hp[k], wp[k], acc);
    out[(img0 + s) * 10 + o] = acc;
  }
}

extern "C" void kernel_launch(void* const* d_in, const int* in_sizes, int n_in,
                              void* d_out, int out_size, void* d_ws,
                              size_t ws_size, hipStream_t stream) {
  const float* x = (const float*)d_in[0];
  const float* conv1_w = (const float*)d_in[1];
  const float* conv1_b = (const float*)d_in[2];
  const float* conv2_w = (const float*)d_in[3];
  const float* conv2_b = (const float*)d_in[4];
  const float* bn2_g = (const float*)d_in[5];
  const float* bn2_b = (const float*)d_in[6];
  const float* conv3_w = (const float*)d_in[7];
  const float* conv3_b = (const float*)d_in[8];
  const float* bn3_g = (const float*)d_in[9];
  const float* bn3_b = (const float*)d_in[10];
  const float* fc1_w = (const float*)d_in[11];
  const float* fc1_b = (const float*)d_in[12];
  const float* fc2_w = (const float*)d_in[13];
  const float* fc2_b = (const float*)d_in[14];
  float* out = (float*)d_out;

  double* sums = (double*)d_ws;
  float* fbase = (float*)((char*)d_ws + DBL_BYTES);
  float* scales = fbase;
  float* w2bp = fbase + W2B_OFF;
  float* w3bT = fbase + W3BT_OFF;
  float* f1b = fbase + FC1B_OFF;
  float* m1 = fbase + H1_OFF;
  float* m2 = fbase + H2_OFF;
  float* y3 = fbase + Y3_OFF;

  hipMemsetAsync(d_ws, 0, DBL_BYTES, stream);
  binarize_k<<<188, 256, 0, stream>>>(conv2_w, conv3_w, fc1_w, w2bp, w3bT, f1b);

  conv1_fused<<<1024, 256, 0, stream>>>(x, conv1_w, conv1_b, m1, sums);
  finalize_bn<<<1, 128, 0, stream>>>(sums + SUM1, sums + SQ1, 6,
                                     1.0 / (8192.0 * 784.0), 1e-4, nullptr,
                                     nullptr, scales + A1, scales + C1);

  conv2_fused<<<1024, 320, 0, stream>>>(m1, w2bp, conv2_b, scales, m2, sums);
  finalize_bn<<<1, 128, 0, stream>>>(sums + SUM2, sums + SQ2, 16,
                                     1.0 / (8192.0 * 100.0), 1e-4, bn2_g, bn2_b,
                                     scales + A2, scales + C2);

  conv3_gemm<<<256, 256, 0, stream>>>(m2, w3bT, conv3_b, scales, y3, sums);
  finalize_bn<<<1, 128, 0, stream>>>(sums + SUM3, sums + SQ3, 120,
                                     1.0 / 8192.0, 1e-5, bn3_g, bn3_b,
                                     scales + A3, scales + C3);

  fc_fused<<<256, 256, 0, stream>>>(y3, scales, f1b, fc1_b, fc2_w, fc2_b, out);
}

// Round 4
// 304.360 us; speedup vs baseline: 2.7570x; 1.0224x over previous
//
#include <hip/hip_runtime.h>

#define DEVFN __device__ __forceinline__

DEVFN float sgnf(float x) { return (x > 0.f) ? 1.f : ((x < 0.f) ? -1.f : 0.f); }

// ---- workspace layout ----
// double region (BN stat accumulators, 64 contention slots per channel)
#define SUM1 0        // 6*64 doubles
#define SQ1  384
#define SUM2 768      // 16*64
#define SQ2  1792
#define SUM3 2816     // 120*64
#define SQ3  10496
#define DBL_BYTES 145408  // 18176 doubles

// float region offsets (in floats, from fbase = ws + DBL_BYTES)
#define A1 0
#define C1 8
#define A2 16
#define C2 32
#define A3 48
#define C3 168
#define W2B_OFF  512                    // 3072 (16x6x32 padded)
#define W3BT_OFF 3584                   // 48000, layout [400][120]
#define FC1B_OFF 51584                  // 10080
#define H1_OFF   65536                  // 8192*1176 (pooled pre-BN layer1)
#define H2_OFF   (H1_OFF + 8192*1176)   // 8192*400  (pooled pre-BN layer2; BN2 applied on load in conv3)
#define Y3_OFF   (H2_OFF + 8192*400)    // 8192*120  (pre-BN layer3)

// ---------------- binarize weights ----------------
__global__ __launch_bounds__(256) void binarize_k(
    const float* __restrict__ w2, const float* __restrict__ w3,
    const float* __restrict__ f1, float* __restrict__ w2bp,
    float* __restrict__ w3bT, float* __restrict__ f1b) {
  int i = blockIdx.x * 256 + threadIdx.x;
  if (i < 3072) {  // padded layout [(c*6+ci)*32 + k], k<25 valid else 0
    int c = i / 192, r = i - c * 192;
    int ci = r / 32, k = r - ci * 32;
    w2bp[i] = (k < 25) ? sgnf(w2[(c * 6 + ci) * 25 + k]) : 0.f;
  }
  if (i < 48000) {
    int c = i / 400, j = i - c * 400;
    w3bT[j * 120 + c] = sgnf(w3[i]);  // transpose for coalesced conv3 reads
  }
  if (i < 10080) f1b[i] = sgnf(f1[i]);
}

// ---------------- layer 1 fused: conv + stats + pre-BN maxpool ----------------
// thread-task = (img, ch, pool-row py): 2 output rows x 28 cols, pooled to 14.
// launch_bounds(256,3): 170-VGPR cap so acc0/acc1/wr/rb stay in registers
// (live set ~123; default heuristic gave 68 VGPRs -> LDS remat per FMA).
__global__ __launch_bounds__(256, 3) void conv1_fused(
    const float* __restrict__ x, const float* __restrict__ w1,
    const float* __restrict__ b1, float* __restrict__ m1,
    double* __restrict__ sums) {
  __shared__ float simg[8 * 1088];   // row stride 34 (bank-conflict pad)
  __shared__ float swtp[6 * 40];     // padded weights, stride 40
  __shared__ float red[6], redq[6];
  int tid = threadIdx.x;
  int img0 = blockIdx.x * 8;
  {
    const float2* xg = (const float2*)(x + (size_t)img0 * 1024);
    for (int i2 = tid; i2 < 4096; i2 += 256) {
      int img = i2 >> 9;
      int r = (i2 >> 4) & 31;
      int c2 = i2 & 15;
      *(float2*)&simg[img * 1088 + r * 34 + c2 * 2] = xg[i2];
    }
  }
  for (int i = tid; i < 240; i += 256) {
    int ch = i / 40, k = i - ch * 40;
    swtp[i] = (k < 25) ? w1[ch * 25 + k] : 0.f;
  }
  if (tid < 6) { red[tid] = 0.f; redq[tid] = 0.f; }
  __syncthreads();

  for (int idx = tid; idx < 672; idx += 256) {
    int img = idx / 84;
    int r = idx - img * 84;
    int ch = r / 14;
    int py = r - ch * 14;
    float wr[25];
    {
      const float4* wp = (const float4*)&swtp[ch * 40];
#pragma unroll
      for (int t = 0; t < 6; ++t) {
        float4 v = wp[t];
        wr[4 * t] = v.x; wr[4 * t + 1] = v.y; wr[4 * t + 2] = v.z; wr[4 * t + 3] = v.w;
      }
      wr[24] = swtp[ch * 40 + 24];
    }
    float bb = b1[ch];
    float acc0[28], acc1[28];
#pragma unroll
    for (int o = 0; o < 28; ++o) { acc0[o] = bb; acc1[o] = bb; }
#pragma unroll
    for (int d = 0; d < 6; ++d) {
      int row = 2 * py + d;
      float rb[32];
      const float2* rp = (const float2*)&simg[img * 1088 + row * 34];
#pragma unroll
      for (int t = 0; t < 16; ++t) { float2 v = rp[t]; rb[2 * t] = v.x; rb[2 * t + 1] = v.y; }
      if (d < 5) {
#pragma unroll
        for (int kx = 0; kx < 5; ++kx) {
          float w = wr[d * 5 + kx];
#pragma unroll
          for (int o = 0; o < 28; ++o) acc0[o] = fmaf(rb[o + kx], w, acc0[o]);
        }
      }
      if (d >= 1) {
#pragma unroll
        for (int kx = 0; kx < 5; ++kx) {
          float w = wr[(d - 1) * 5 + kx];
#pragma unroll
          for (int o = 0; o < 28; ++o) acc1[o] = fmaf(rb[o + kx], w, acc1[o]);
        }
      }
    }
    float s = 0.f, s2 = 0.f;
#pragma unroll
    for (int o = 0; o < 28; ++o) {
      s += acc0[o] + acc1[o];
      s2 = fmaf(acc0[o], acc0[o], s2);
      s2 = fmaf(acc1[o], acc1[o], s2);
    }
    atomicAdd(&red[ch], s);
    atomicAdd(&redq[ch], s2);
    float* mp = m1 + (size_t)(img0 + img) * 1176 + ch * 196 + py * 14;
#pragma unroll
    for (int j = 0; j < 7; ++j) {
      float2 v;
      v.x = fmaxf(fmaxf(acc0[4 * j], acc0[4 * j + 1]), fmaxf(acc1[4 * j], acc1[4 * j + 1]));
      v.y = fmaxf(fmaxf(acc0[4 * j + 2], acc0[4 * j + 3]), fmaxf(acc1[4 * j + 2], acc1[4 * j + 3]));
      *(float2*)&mp[2 * j] = v;
    }
  }
  __syncthreads();
  if (tid < 6) {
    int slot = blockIdx.x & 63;
    atomicAdd(&sums[SUM1 + tid * 64 + slot], (double)red[tid]);
    atomicAdd(&sums[SQ1 + tid * 64 + slot], (double)redq[tid]);
  }
}

// ---------------- BN finalize: a = g*rsqrt(var+eps), c = beta - mean*a ------
__global__ __launch_bounds__(128) void finalize_bn(
    const double* __restrict__ sum, const double* __restrict__ sq, int nch,
    double invN, double eps, const float* __restrict__ gamma,
    const float* __restrict__ beta, float* __restrict__ a,
    float* __restrict__ c) {
  int ch = threadIdx.x;
  if (ch >= nch) return;
  double s = 0.0, q = 0.0;
  for (int k = 0; k < 64; ++k) {
    s += sum[ch * 64 + k];
    q += sq[ch * 64 + k];
  }
  double mean = s * invN;
  double var = q * invN - mean * mean;
  float inv = (float)(1.0 / sqrt(var + eps));
  float g = gamma ? fmaxf(gamma[ch], 0.01f) : 1.f;
  float av = g * inv;
  float cv = (beta ? beta[ch] : 0.f) - (float)mean * av;
  a[ch] = av;
  c[ch] = cv;
}

// ---------------- layer 2 fused: BN1+relu on load, conv + stats + pre-BN pool
// block = 640 threads; task = (ch, py, img): 1ch x 2rows x 10 cols -> 1x5 pooled.
// One channel per thread keeps live set ~71 floats; (640,5) caps VGPR at 102.
__global__ __launch_bounds__(640, 5) void conv2_fused(
    const float* __restrict__ m1, const float* __restrict__ w2bp,
    const float* __restrict__ b2, const float* __restrict__ scales,
    float* __restrict__ m2, double* __restrict__ sums) {
  __shared__ float sh1[8 * 1176];
  __shared__ float swt[3072];
  __shared__ float sa1[6], sc1[6];
  __shared__ float red[16], redq[16];
  int tid = threadIdx.x;
  int img0 = blockIdx.x * 8;
  if (tid < 6) { sa1[tid] = scales[A1 + tid]; sc1[tid] = scales[C1 + tid]; }
  if (tid < 16) { red[tid] = 0.f; redq[tid] = 0.f; }
  __syncthreads();
  {
    const float4* mg = (const float4*)(m1 + (size_t)img0 * 1176);
    float4* s4 = (float4*)sh1;
    for (int i4 = tid; i4 < 2352; i4 += 640) {
      int ch = (i4 % 294) / 49;  // 49 float4 per (ch,row-block) of 196
      float a = sa1[ch], c = sc1[ch];
      float4 v = mg[i4];
      v.x = fmaxf(fmaf(a, v.x, c), 0.f);
      v.y = fmaxf(fmaf(a, v.y, c), 0.f);
      v.z = fmaxf(fmaf(a, v.z, c), 0.f);
      v.w = fmaxf(fmaf(a, v.w, c), 0.f);
      s4[i4] = v;
    }
    const float4* wg = (const float4*)w2bp;
    float4* w4 = (float4*)swt;
    for (int i4 = tid; i4 < 768; i4 += 640) w4[i4] = wg[i4];
  }
  __syncthreads();

  // task decode: img fastest so a wave spans <=2 channels (weight broadcast)
  int ch = tid / 40;
  int r = tid - ch * 40;
  int py = r >> 3;
  int img = r & 7;
  float acc[2][10];
  float bb = b2[ch];
#pragma unroll
  for (int o = 0; o < 10; ++o) { acc[0][o] = bb; acc[1][o] = bb; }
  for (int ci = 0; ci < 6; ++ci) {
    float w[25];
    {
      const float4* p0 = (const float4*)&swt[(ch * 6 + ci) * 32];
#pragma unroll
      for (int t = 0; t < 6; ++t) {
        float4 a = p0[t];
        w[4 * t] = a.x; w[4 * t + 1] = a.y; w[4 * t + 2] = a.z; w[4 * t + 3] = a.w;
      }
      w[24] = swt[(ch * 6 + ci) * 32 + 24];
    }
    const float* base = &sh1[img * 1176 + ci * 196 + 28 * py];
#pragma unroll
    for (int d = 0; d < 6; ++d) {
      float rb[14];
      const float2* rp = (const float2*)(base + d * 14);
#pragma unroll
      for (int t = 0; t < 7; ++t) { float2 v = rp[t]; rb[2 * t] = v.x; rb[2 * t + 1] = v.y; }
      if (d < 5) {
#pragma unroll
        for (int kx = 0; kx < 5; ++kx) {
          float wa = w[d * 5 + kx];
#pragma unroll
          for (int o = 0; o < 10; ++o) acc[0][o] = fmaf(rb[o + kx], wa, acc[0][o]);
        }
      }
      if (d >= 1) {
#pragma unroll
        for (int kx = 0; kx < 5; ++kx) {
          float wa = w[(d - 1) * 5 + kx];
#pragma unroll
          for (int o = 0; o < 10; ++o) acc[1][o] = fmaf(rb[o + kx], wa, acc[1][o]);
        }
      }
    }
  }
  float s0 = 0.f, q0 = 0.f;
#pragma unroll
  for (int rr = 0; rr < 2; ++rr)
#pragma unroll
    for (int o = 0; o < 10; ++o) {
      float v0 = acc[rr][o];
      s0 += v0; q0 = fmaf(v0, v0, q0);
    }
  atomicAdd(&red[ch], s0); atomicAdd(&redq[ch], q0);
  {
    float* mp0 = m2 + (size_t)(img0 + img) * 400 + ch * 25 + py * 5;
#pragma unroll
    for (int i = 0; i < 5; ++i) {
      mp0[i] = fmaxf(fmaxf(acc[0][2 * i], acc[0][2 * i + 1]),
                     fmaxf(acc[1][2 * i], acc[1][2 * i + 1]));
    }
  }
  __syncthreads();
  if (tid < 16) {
    int slot = blockIdx.x & 63;
    atomicAdd(&sums[SUM2 + tid * 64 + slot], (double)red[tid]);
    atomicAdd(&sums[SQ2 + tid * 64 + slot], (double)redq[tid]);
  }
}

// ---------------- layer 3: LDS-tiled GEMM, BN2+relu fused on A-load, + stats
// grid 256, block 256. M-tile=32 imgs, N=120 (pad 128), K=400 in 4 chunks.
// per-thread 4 imgs x 4 ch register tile. A stored k-major for b128 reads.
__global__ __launch_bounds__(256) void conv3_gemm(
    const float* __restrict__ m2, const float* __restrict__ w3bT,
    const float* __restrict__ b3, const float* __restrict__ scales,
    float* __restrict__ y3, double* __restrict__ sums) {
  __shared__ float sA[100 * 36];    // [k][img], img-dim padded 32->36
  __shared__ float sB[100 * 128];   // [k][ch], ch padded 120->128 (zeros)
  __shared__ float red[128], redq[128];
  __shared__ float sa2[16], sc2[16];
  int tid = threadIdx.x;
  int img0 = blockIdx.x * 32;
  if (tid < 128) { red[tid] = 0.f; redq[tid] = 0.f; }
  if (tid >= 128 && tid < 144) {
    sa2[tid - 128] = scales[A2 + tid - 128];
    sc2[tid - 128] = scales[C2 + tid - 128];
  }
  int tx = tid & 31, ty = tid >> 5;
  int c0 = tx * 4;
  float acc[4][4] = {};
  for (int kc = 0; kc < 400; kc += 100) {
    __syncthreads();  // also covers sa2/red init before first staging
    // stage A: 32 imgs x 100 k, transpose to k-major, BN2+relu applied
    for (int i4 = tid; i4 < 800; i4 += 256) {
      int i = i4 / 25, t = i4 - i * 25;
      float4 v = *(const float4*)(m2 + (size_t)(img0 + i) * 400 + kc + t * 4);
      int jj = t * 4;
      float vv[4] = {v.x, v.y, v.z, v.w};
#pragma unroll
      for (int e = 0; e < 4; ++e) {
        int ch = (kc + jj + e) / 25;
        sA[(jj + e) * 36 + i] = fmaxf(fmaf(sa2[ch], vv[e], sc2[ch]), 0.f);
      }
    }
    // stage B: 100 k x 120 ch (+8 zero pad)
    for (int i4 = tid; i4 < 3200; i4 += 256) {
      int j = i4 >> 5, c4 = i4 & 31;
      float4 v;
      if (c4 < 30)
        v = *(const float4*)(w3bT + (size_t)(kc + j) * 120 + c4 * 4);
      else
        v = make_float4(0.f, 0.f, 0.f, 0.f);
      *(float4*)(sB + j * 128 + c4 * 4) = v;
    }
    __syncthreads();
#pragma unroll 2
    for (int j = 0; j < 100; ++j) {
      float4 a = *(const float4*)(sA + j * 36 + ty * 4);
      float4 b = *(const float4*)(sB + j * 128 + c0);
      acc[0][0] = fmaf(a.x, b.x, acc[0][0]);
      acc[0][1] = fmaf(a.x, b.y, acc[0][1]);
      acc[0][2] = fmaf(a.x, b.z, acc[0][2]);
      acc[0][3] = fmaf(a.x, b.w, acc[0][3]);
      acc[1][0] = fmaf(a.y, b.x, acc[1][0]);
      acc[1][1] = fmaf(a.y, b.y, acc[1][1]);
      acc[1][2] = fmaf(a.y, b.z, acc[1][2]);
      acc[1][3] = fmaf(a.y, b.w, acc[1][3]);
      acc[2][0] = fmaf(a.z, b.x, acc[2][0]);
      acc[2][1] = fmaf(a.z, b.y, acc[2][1]);
      acc[2][2] = fmaf(a.z, b.z, acc[2][2]);
      acc[2][3] = fmaf(a.z, b.w, acc[2][3]);
      acc[3][0] = fmaf(a.w, b.x, acc[3][0]);
      acc[3][1] = fmaf(a.w, b.y, acc[3][1]);
      acc[3][2] = fmaf(a.w, b.z, acc[3][2]);
      acc[3][3] = fmaf(a.w, b.w, acc[3][3]);
    }
  }
  // epilogue: +bias, write y3, accumulate stats
  if (c0 < 120) {
    float4 bias = *(const float4*)(b3 + c0);
    float sc[4] = {0.f, 0.f, 0.f, 0.f}, sq[4] = {0.f, 0.f, 0.f, 0.f};
#pragma unroll
    for (int i = 0; i < 4; ++i) {
      float4 v;
      v.x = acc[i][0] + bias.x;
      v.y = acc[i][1] + bias.y;
      v.z = acc[i][2] + bias.z;
      v.w = acc[i][3] + bias.w;
      *(float4*)(y3 + (size_t)(img0 + ty * 4 + i) * 120 + c0) = v;
      sc[0] += v.x; sq[0] = fmaf(v.x, v.x, sq[0]);
      sc[1] += v.y; sq[1] = fmaf(v.y, v.y, sq[1]);
      sc[2] += v.z; sq[2] = fmaf(v.z, v.z, sq[2]);
      sc[3] += v.w; sq[3] = fmaf(v.w, v.w, sq[3]);
    }
#pragma unroll
    for (int c = 0; c < 4; ++c) {
      atomicAdd(&red[c0 + c], sc[c]);
      atomicAdd(&redq[c0 + c], sq[c]);
    }
  }
  __syncthreads();
  if (tid < 120) {
    int slot = blockIdx.x & 63;
    atomicAdd(&sums[SUM3 + tid * 64 + slot], (double)red[tid]);
    atomicAdd(&sums[SQ3 + tid * 64 + slot], (double)redq[tid]);
  }
}

// ---------------- fc1(binary)+relu -> fc2 fused, BN3+relu on load ----------
__global__ __launch_bounds__(256) void fc_fused(
    const float* __restrict__ y3, const float* __restrict__ scales,
    const float* __restrict__ f1b, const float* __restrict__ b1,
    const float* __restrict__ w2, const float* __restrict__ b2,
    float* __restrict__ out) {
  __shared__ float sh3[32 * 121];
  __shared__ float sh4[32 * 85];
  __shared__ float sw2[10 * 85];
  __shared__ float sa3[120], sc3[120];
  __shared__ float sb1[84], sb2[10];
  int tid = threadIdx.x;
  int img0 = blockIdx.x * 32;
  if (tid < 120) { sa3[tid] = scales[A3 + tid]; sc3[tid] = scales[C3 + tid]; }
  if (tid >= 128 && tid < 212) sb1[tid - 128] = b1[tid - 128];
  if (tid >= 216 && tid < 226) sb2[tid - 216] = b2[tid - 216];
  __syncthreads();
  for (int i = tid; i < 32 * 120; i += 256) {
    int s = i / 120, k = i - s * 120;
    sh3[s * 121 + k] = fmaxf(fmaf(sa3[k], y3[(size_t)img0 * 120 + i], sc3[k]), 0.f);
  }
  for (int i = tid; i < 840; i += 256) {
    int o = i / 84, k = i - o * 84;
    sw2[o * 85 + k] = w2[i];
  }
  __syncthreads();
  for (int idx = tid; idx < 32 * 84; idx += 256) {
    int s = idx / 84, j = idx - s * 84;
    float acc = sb1[j];
    const float* wp = f1b + j * 120;
    const float* hp = &sh3[s * 121];
#pragma unroll 4
    for (int k = 0; k < 120; ++k) acc = fmaf(hp[k], wp[k], acc);
    sh4[s * 85 + j] = fmaxf(acc, 0.f);
  }
  __syncthreads();
  for (int idx = tid; idx < 320; idx += 256) {
    int s = idx / 10, o = idx - s * 10;
    float acc = sb2[o];
    const float* hp = &sh4[s * 85];
    const float* wp = &sw2[o * 85];
#pragma unroll 4
    for (int k = 0; k < 84; ++k) acc = fmaf(hp[k], wp[k], acc);
    out[(img0 + s) * 10 + o] = acc;
  }
}

extern "C" void kernel_launch(void* const* d_in, const int* in_sizes, int n_in,
                              void* d_out, int out_size, void* d_ws,
                              size_t ws_size, hipStream_t stream) {
  const float* x = (const float*)d_in[0];
  const float* conv1_w = (const float*)d_in[1];
  const float* conv1_b = (const float*)d_in[2];
  const float* conv2_w = (const float*)d_in[3];
  const float* conv2_b = (const float*)d_in[4];
  const float* bn2_g = (const float*)d_in[5];
  const float* bn2_b = (const float*)d_in[6];
  const float* conv3_w = (const float*)d_in[7];
  const float* conv3_b = (const float*)d_in[8];
  const float* bn3_g = (const float*)d_in[9];
  const float* bn3_b = (const float*)d_in[10];
  const float* fc1_w = (const float*)d_in[11];
  const float* fc1_b = (const float*)d_in[12];
  const float* fc2_w = (const float*)d_in[13];
  const float* fc2_b = (const float*)d_in[14];
  float* out = (float*)d_out;

  double* sums = (double*)d_ws;
  float* fbase = (float*)((char*)d_ws + DBL_BYTES);
  float* scales = fbase;
  float* w2bp = fbase + W2B_OFF;
  float* w3bT = fbase + W3BT_OFF;
  float* f1b = fbase + FC1B_OFF;
  float* m1 = fbase + H1_OFF;
  float* m2 = fbase + H2_OFF;
  float* y3 = fbase + Y3_OFF;

  hipMemsetAsync(d_ws, 0, DBL_BYTES, stream);
  binarize_k<<<188, 256, 0, stream>>>(conv2_w, conv3_w, fc1_w, w2bp, w3bT, f1b);

  conv1_fused<<<1024, 256, 0, stream>>>(x, conv1_w, conv1_b, m1, sums);
  finalize_bn<<<1, 128, 0, stream>>>(sums + SUM1, sums + SQ1, 6,
                                     1.0 / (8192.0 * 784.0), 1e-4, nullptr,
                                     nullptr, scales + A1, scales + C1);

  conv2_fused<<<1024, 640, 0, stream>>>(m1, w2bp, conv2_b, scales, m2, sums);
  finalize_bn<<<1, 128, 0, stream>>>(sums + SUM2, sums + SQ2, 16,
                                     1.0 / (8192.0 * 100.0), 1e-4, bn2_g, bn2_b,
                                     scales + A2, scales + C2);

  conv3_gemm<<<256, 256, 0, stream>>>(m2, w3bT, conv3_b, scales, y3, sums);
  finalize_bn<<<1, 128, 0, stream>>>(sums + SUM3, sums + SQ3, 120,
                                     1.0 / 8192.0, 1e-5, bn3_g, bn3_b,
                                     scales + A3, scales + C3);

  fc_fused<<<256, 256, 0, stream>>>(y3, scales, f1b, fc1_b, fc2_w, fc2_b, out);
}

// Round 5
// 299.542 us; speedup vs baseline: 2.8013x; 1.0161x over previous
//
#include <hip/hip_runtime.h>

#define DEVFN __device__ __forceinline__

DEVFN float sgnf(float x) { return (x > 0.f) ? 1.f : ((x < 0.f) ? -1.f : 0.f); }

// ---- workspace layout ----
// double region (BN stat accumulators, 64 contention slots per channel)
#define SUM1 0        // 6*64 doubles
#define SQ1  384
#define SUM2 768      // 16*64
#define SQ2  1792
#define SUM3 2816     // 120*64
#define SQ3  10496
#define DBL_BYTES 145408  // 18176 doubles

// float region offsets (in floats, from fbase = ws + DBL_BYTES)
#define A1 0
#define C1 8
#define A2 16
#define C2 32
#define A3 48
#define C3 168
#define W2B_OFF  512                    // 2400: w2 binarized, layout [ci][k][ch16]
#define W3BT_OFF 3584                   // 48000, layout [400][120]
#define FC1B_OFF 51584                  // 10080
#define H1_OFF   65536                  // 8192*1176 (pooled pre-BN layer1)
#define H2_OFF   (H1_OFF + 8192*1176)   // 8192*400  (pooled pre-BN layer2; BN2 applied on load in conv3)
#define Y3_OFF   (H2_OFF + 8192*400)    // 8192*120  (pre-BN layer3)

// ---------------- binarize weights ----------------
__global__ __launch_bounds__(256) void binarize_k(
    const float* __restrict__ w2, const float* __restrict__ w3,
    const float* __restrict__ f1, float* __restrict__ w2t,
    float* __restrict__ w3bT, float* __restrict__ f1b) {
  int i = blockIdx.x * 256 + threadIdx.x;
  if (i < 2400) {  // [ci][k][ch]: i = ci*400 + k*16 + ch
    int ci = i / 400, r = i - ci * 400;
    int k = r >> 4, ch = r & 15;
    w2t[i] = sgnf(w2[(ch * 6 + ci) * 25 + k]);
  }
  if (i < 48000) {
    int c = i / 400, j = i - c * 400;
    w3bT[j * 120 + c] = sgnf(w3[i]);  // transpose for coalesced conv3 reads
  }
  if (i < 10080) f1b[i] = sgnf(f1[i]);
}

// ---------------- layer 1 fused: conv + stats + pre-BN maxpool ----------------
// thread-task = (img, ch, pool-row py): 2 output rows x 28 cols, pooled to 14.
__global__ __launch_bounds__(256, 3) void conv1_fused(
    const float* __restrict__ x, const float* __restrict__ w1,
    const float* __restrict__ b1, float* __restrict__ m1,
    double* __restrict__ sums) {
  __shared__ float simg[8 * 1088];   // row stride 34 (bank-conflict pad)
  __shared__ float swtp[6 * 40];     // padded weights, stride 40
  __shared__ float red[6], redq[6];
  int tid = threadIdx.x;
  int img0 = blockIdx.x * 8;
  {
    const float2* xg = (const float2*)(x + (size_t)img0 * 1024);
    for (int i2 = tid; i2 < 4096; i2 += 256) {
      int img = i2 >> 9;
      int r = (i2 >> 4) & 31;
      int c2 = i2 & 15;
      *(float2*)&simg[img * 1088 + r * 34 + c2 * 2] = xg[i2];
    }
  }
  for (int i = tid; i < 240; i += 256) {
    int ch = i / 40, k = i - ch * 40;
    swtp[i] = (k < 25) ? w1[ch * 25 + k] : 0.f;
  }
  if (tid < 6) { red[tid] = 0.f; redq[tid] = 0.f; }
  __syncthreads();

  for (int idx = tid; idx < 672; idx += 256) {
    int img = idx / 84;
    int r = idx - img * 84;
    int ch = r / 14;
    int py = r - ch * 14;
    float wr[25];
    {
      const float4* wp = (const float4*)&swtp[ch * 40];
#pragma unroll
      for (int t = 0; t < 6; ++t) {
        float4 v = wp[t];
        wr[4 * t] = v.x; wr[4 * t + 1] = v.y; wr[4 * t + 2] = v.z; wr[4 * t + 3] = v.w;
      }
      wr[24] = swtp[ch * 40 + 24];
    }
    float bb = b1[ch];
    float acc0[28], acc1[28];
#pragma unroll
    for (int o = 0; o < 28; ++o) { acc0[o] = bb; acc1[o] = bb; }
#pragma unroll
    for (int d = 0; d < 6; ++d) {
      int row = 2 * py + d;
      float rb[32];
      const float2* rp = (const float2*)&simg[img * 1088 + row * 34];
#pragma unroll
      for (int t = 0; t < 16; ++t) { float2 v = rp[t]; rb[2 * t] = v.x; rb[2 * t + 1] = v.y; }
      if (d < 5) {
#pragma unroll
        for (int kx = 0; kx < 5; ++kx) {
          float w = wr[d * 5 + kx];
#pragma unroll
          for (int o = 0; o < 28; ++o) acc0[o] = fmaf(rb[o + kx], w, acc0[o]);
        }
      }
      if (d >= 1) {
#pragma unroll
        for (int kx = 0; kx < 5; ++kx) {
          float w = wr[(d - 1) * 5 + kx];
#pragma unroll
          for (int o = 0; o < 28; ++o) acc1[o] = fmaf(rb[o + kx], w, acc1[o]);
        }
      }
    }
    float s = 0.f, s2 = 0.f;
#pragma unroll
    for (int o = 0; o < 28; ++o) {
      s += acc0[o] + acc1[o];
      s2 = fmaf(acc0[o], acc0[o], s2);
      s2 = fmaf(acc1[o], acc1[o], s2);
    }
    atomicAdd(&red[ch], s);
    atomicAdd(&redq[ch], s2);
    float* mp = m1 + (size_t)(img0 + img) * 1176 + ch * 196 + py * 14;
#pragma unroll
    for (int j = 0; j < 7; ++j) {
      float2 v;
      v.x = fmaxf(fmaxf(acc0[4 * j], acc0[4 * j + 1]), fmaxf(acc1[4 * j], acc1[4 * j + 1]));
      v.y = fmaxf(fmaxf(acc0[4 * j + 2], acc0[4 * j + 3]), fmaxf(acc1[4 * j + 2], acc1[4 * j + 3]));
      *(float2*)&mp[2 * j] = v;
    }
  }
  __syncthreads();
  if (tid < 6) {
    int slot = blockIdx.x & 63;
    atomicAdd(&sums[SUM1 + tid * 64 + slot], (double)red[tid]);
    atomicAdd(&sums[SQ1 + tid * 64 + slot], (double)redq[tid]);
  }
}

// ---------------- BN finalize: a = g*rsqrt(var+eps), c = beta - mean*a ------
__global__ __launch_bounds__(128) void finalize_bn(
    const double* __restrict__ sum, const double* __restrict__ sq, int nch,
    double invN, double eps, const float* __restrict__ gamma,
    const float* __restrict__ beta, float* __restrict__ a,
    float* __restrict__ c) {
  int ch = threadIdx.x;
  if (ch >= nch) return;
  double s = 0.0, q = 0.0;
  for (int k = 0; k < 64; ++k) {
    s += sum[ch * 64 + k];
    q += sq[ch * 64 + k];
  }
  double mean = s * invN;
  double var = q * invN - mean * mean;
  float inv = (float)(1.0 / sqrt(var + eps));
  float g = gamma ? fmaxf(gamma[ch], 0.01f) : 1.f;
  float av = g * inv;
  float cv = (beta ? beta[ch] : 0.f) - (float)mean * av;
  a[ch] = av;
  c[ch] = cv;
}

// ---------------- layer 2 fused: BN1+relu on load, conv + stats + pre-BN pool
// block 256 = 16ch x 8img x 2half. Wave = 16ch x 4img -> activation reads are
// 16-lane broadcast (4 unique addrs/wave, ~0 conflicts); weight reads hit 16
// consecutive banks via [ci][k][ch] layout. Rows padded to 16 -> b128 reads.
// half 0: pooled rows 0-1; half 1: pooled rows 2-4.
__global__ __launch_bounds__(256, 4) void conv2_fused(
    const float* __restrict__ m1, const float* __restrict__ w2t,
    const float* __restrict__ b2, const float* __restrict__ scales,
    float* __restrict__ m2, double* __restrict__ sums) {
  __shared__ float sh1[8 * 1344];   // 8 img x 6 planes x 14 rows x 16 (pad)
  __shared__ float swt[2400];       // [ci][k][ch16]
  __shared__ float sa1[6], sc1[6];
  __shared__ float red[16], redq[16];
  int tid = threadIdx.x;
  int img0 = blockIdx.x * 8;
  if (tid < 6) { sa1[tid] = scales[A1 + tid]; sc1[tid] = scales[C1 + tid]; }
  if (tid < 16) { red[tid] = 0.f; redq[tid] = 0.f; }
  __syncthreads();
  {
    const float4* wg = (const float4*)w2t;
    float4* w4 = (float4*)swt;
    for (int i4 = tid; i4 < 600; i4 += 256) w4[i4] = wg[i4];
  }
  {
    const float2* mg = (const float2*)(m1 + (size_t)img0 * 1176);
    for (int i2 = tid; i2 < 4704; i2 += 256) {
      int img = i2 / 588;
      int r = i2 - img * 588;
      int pl = r / 98;
      int rr = r - pl * 98;
      int row = rr / 7, t = rr - row * 7;
      float a = sa1[pl], c = sc1[pl];
      float2 v = mg[i2];
      v.x = fmaxf(fmaf(a, v.x, c), 0.f);
      v.y = fmaxf(fmaf(a, v.y, c), 0.f);
      *(float2*)&sh1[img * 1344 + pl * 224 + row * 16 + t * 2] = v;
    }
  }
  __syncthreads();

  int ch = tid & 15;
  int img = (tid >> 4) & 7;
  int half = tid >> 7;
  float bb = b2[ch];
  float s0 = 0.f, q0 = 0.f;
  int pr_lo = half ? 2 : 0;
  int pr_hi = half ? 5 : 2;
  const float* ibase = &sh1[img * 1344];
  float* mpo = m2 + (size_t)(img0 + img) * 400 + ch * 25;
  for (int pr = pr_lo; pr < pr_hi; ++pr) {
    float acc[2][10];
#pragma unroll
    for (int o = 0; o < 10; ++o) { acc[0][o] = bb; acc[1][o] = bb; }
    for (int ci = 0; ci < 6; ++ci) {
      float w[25];
#pragma unroll
      for (int k = 0; k < 25; ++k) w[k] = swt[ci * 400 + k * 16 + ch];
      const float* rbase = ibase + ci * 224 + pr * 32;
#pragma unroll
      for (int d = 0; d < 6; ++d) {
        float rb[16];
        const float4* rp = (const float4*)(rbase + d * 16);
#pragma unroll
        for (int t = 0; t < 4; ++t) {
          float4 v = rp[t];
          rb[4 * t] = v.x; rb[4 * t + 1] = v.y; rb[4 * t + 2] = v.z; rb[4 * t + 3] = v.w;
        }
        if (d < 5) {
#pragma unroll
          for (int kx = 0; kx < 5; ++kx) {
            float wv = w[d * 5 + kx];
#pragma unroll
            for (int o = 0; o < 10; ++o) acc[0][o] = fmaf(rb[o + kx], wv, acc[0][o]);
          }
        }
        if (d >= 1) {
#pragma unroll
          for (int kx = 0; kx < 5; ++kx) {
            float wv = w[(d - 1) * 5 + kx];
#pragma unroll
            for (int o = 0; o < 10; ++o) acc[1][o] = fmaf(rb[o + kx], wv, acc[1][o]);
          }
        }
      }
    }
#pragma unroll
    for (int rr2 = 0; rr2 < 2; ++rr2)
#pragma unroll
      for (int o = 0; o < 10; ++o) {
        float v = acc[rr2][o];
        s0 += v;
        q0 = fmaf(v, v, q0);
      }
#pragma unroll
    for (int pc = 0; pc < 5; ++pc)
      mpo[pr * 5 + pc] = fmaxf(fmaxf(acc[0][2 * pc], acc[0][2 * pc + 1]),
                               fmaxf(acc[1][2 * pc], acc[1][2 * pc + 1]));
  }
  // reduce stats over the 4 img lanes in each wave, then 16 atomics/wave
  s0 += __shfl_xor(s0, 16, 64); q0 += __shfl_xor(q0, 16, 64);
  s0 += __shfl_xor(s0, 32, 64); q0 += __shfl_xor(q0, 32, 64);
  if ((tid & 48) == 0) {
    atomicAdd(&red[ch], s0);
    atomicAdd(&redq[ch], q0);
  }
  __syncthreads();
  if (tid < 16) {
    int slot = blockIdx.x & 63;
    atomicAdd(&sums[SUM2 + tid * 64 + slot], (double)red[tid]);
    atomicAdd(&sums[SQ2 + tid * 64 + slot], (double)redq[tid]);
  }
}

// ---------------- layer 3: LDS-tiled GEMM, BN2+relu fused on A-load, + stats
// grid 256, block 256. M-tile=32 imgs, N=120 (pad 128), K=400 in 4 chunks.
// per-thread 4 imgs x 4 ch register tile. A stored k-major for b128 reads.
__global__ __launch_bounds__(256) void conv3_gemm(
    const float* __restrict__ m2, const float* __restrict__ w3bT,
    const float* __restrict__ b3, const float* __restrict__ scales,
    float* __restrict__ y3, double* __restrict__ sums) {
  __shared__ float sA[100 * 36];    // [k][img], img-dim padded 32->36
  __shared__ float sB[100 * 128];   // [k][ch], ch padded 120->128 (zeros)
  __shared__ float red[128], redq[128];
  __shared__ float sa2[16], sc2[16];
  int tid = threadIdx.x;
  int img0 = blockIdx.x * 32;
  if (tid < 128) { red[tid] = 0.f; redq[tid] = 0.f; }
  if (tid >= 128 && tid < 144) {
    sa2[tid - 128] = scales[A2 + tid - 128];
    sc2[tid - 128] = scales[C2 + tid - 128];
  }
  int tx = tid & 31, ty = tid >> 5;
  int c0 = tx * 4;
  float acc[4][4] = {};
  for (int kc = 0; kc < 400; kc += 100) {
    __syncthreads();  // also covers sa2/red init before first staging
    // stage A: 32 imgs x 100 k, transpose to k-major, BN2+relu applied
    for (int i4 = tid; i4 < 800; i4 += 256) {
      int i = i4 / 25, t = i4 - i * 25;
      float4 v = *(const float4*)(m2 + (size_t)(img0 + i) * 400 + kc + t * 4);
      int jj = t * 4;
      float vv[4] = {v.x, v.y, v.z, v.w};
#pragma unroll
      for (int e = 0; e < 4; ++e) {
        int ch = (kc + jj + e) / 25;
        sA[(jj + e) * 36 + i] = fmaxf(fmaf(sa2[ch], vv[e], sc2[ch]), 0.f);
      }
    }
    // stage B: 100 k x 120 ch (+8 zero pad)
    for (int i4 = tid; i4 < 3200; i4 += 256) {
      int j = i4 >> 5, c4 = i4 & 31;
      float4 v;
      if (c4 < 30)
        v = *(const float4*)(w3bT + (size_t)(kc + j) * 120 + c4 * 4);
      else
        v = make_float4(0.f, 0.f, 0.f, 0.f);
      *(float4*)(sB + j * 128 + c4 * 4) = v;
    }
    __syncthreads();
#pragma unroll 2
    for (int j = 0; j < 100; ++j) {
      float4 a = *(const float4*)(sA + j * 36 + ty * 4);
      float4 b = *(const float4*)(sB + j * 128 + c0);
      acc[0][0] = fmaf(a.x, b.x, acc[0][0]);
      acc[0][1] = fmaf(a.x, b.y, acc[0][1]);
      acc[0][2] = fmaf(a.x, b.z, acc[0][2]);
      acc[0][3] = fmaf(a.x, b.w, acc[0][3]);
      acc[1][0] = fmaf(a.y, b.x, acc[1][0]);
      acc[1][1] = fmaf(a.y, b.y, acc[1][1]);
      acc[1][2] = fmaf(a.y, b.z, acc[1][2]);
      acc[1][3] = fmaf(a.y, b.w, acc[1][3]);
      acc[2][0] = fmaf(a.z, b.x, acc[2][0]);
      acc[2][1] = fmaf(a.z, b.y, acc[2][1]);
      acc[2][2] = fmaf(a.z, b.z, acc[2][2]);
      acc[2][3] = fmaf(a.z, b.w, acc[2][3]);
      acc[3][0] = fmaf(a.w, b.x, acc[3][0]);
      acc[3][1] = fmaf(a.w, b.y, acc[3][1]);
      acc[3][2] = fmaf(a.w, b.z, acc[3][2]);
      acc[3][3] = fmaf(a.w, b.w, acc[3][3]);
    }
  }
  // epilogue: +bias, write y3, accumulate stats
  if (c0 < 120) {
    float4 bias = *(const float4*)(b3 + c0);
    float sc[4] = {0.f, 0.f, 0.f, 0.f}, sq[4] = {0.f, 0.f, 0.f, 0.f};
#pragma unroll
    for (int i = 0; i < 4; ++i) {
      float4 v;
      v.x = acc[i][0] + bias.x;
      v.y = acc[i][1] + bias.y;
      v.z = acc[i][2] + bias.z;
      v.w = acc[i][3] + bias.w;
      *(float4*)(y3 + (size_t)(img0 + ty * 4 + i) * 120 + c0) = v;
      sc[0] += v.x; sq[0] = fmaf(v.x, v.x, sq[0]);
      sc[1] += v.y; sq[1] = fmaf(v.y, v.y, sq[1]);
      sc[2] += v.z; sq[2] = fmaf(v.z, v.z, sq[2]);
      sc[3] += v.w; sq[3] = fmaf(v.w, v.w, sq[3]);
    }
#pragma unroll
    for (int c = 0; c < 4; ++c) {
      atomicAdd(&red[c0 + c], sc[c]);
      atomicAdd(&redq[c0 + c], sq[c]);
    }
  }
  __syncthreads();
  if (tid < 120) {
    int slot = blockIdx.x & 63;
    atomicAdd(&sums[SUM3 + tid * 64 + slot], (double)red[tid]);
    atomicAdd(&sums[SQ3 + tid * 64 + slot], (double)redq[tid]);
  }
}

// ---------------- fc1(binary)+relu -> fc2 fused, BN3+relu on load ----------
__global__ __launch_bounds__(256) void fc_fused(
    const float* __restrict__ y3, const float* __restrict__ scales,
    const float* __restrict__ f1b, const float* __restrict__ b1,
    const float* __restrict__ w2, const float* __restrict__ b2,
    float* __restrict__ out) {
  __shared__ float sh3[32 * 121];
  __shared__ float sh4[32 * 85];
  __shared__ float sw2[10 * 85];
  __shared__ float sa3[120], sc3[120];
  __shared__ float sb1[84], sb2[10];
  int tid = threadIdx.x;
  int img0 = blockIdx.x * 32;
  if (tid < 120) { sa3[tid] = scales[A3 + tid]; sc3[tid] = scales[C3 + tid]; }
  if (tid >= 128 && tid < 212) sb1[tid - 128] = b1[tid - 128];
  if (tid >= 216 && tid < 226) sb2[tid - 216] = b2[tid - 216];
  __syncthreads();
  for (int i = tid; i < 32 * 120; i += 256) {
    int s = i / 120, k = i - s * 120;
    sh3[s * 121 + k] = fmaxf(fmaf(sa3[k], y3[(size_t)img0 * 120 + i], sc3[k]), 0.f);
  }
  for (int i = tid; i < 840; i += 256) {
    int o = i / 84, k = i - o * 84;
    sw2[o * 85 + k] = w2[i];
  }
  __syncthreads();
  for (int idx = tid; idx < 32 * 84; idx += 256) {
    int s = idx / 84, j = idx - s * 84;
    float acc = sb1[j];
    const float* wp = f1b + j * 120;
    const float* hp = &sh3[s * 121];
#pragma unroll 4
    for (int k = 0; k < 120; ++k) acc = fmaf(hp[k], wp[k], acc);
    sh4[s * 85 + j] = fmaxf(acc, 0.f);
  }
  __syncthreads();
  for (int idx = tid; idx < 320; idx += 256) {
    int s = idx / 10, o = idx - s * 10;
    float acc = sb2[o];
    const float* hp = &sh4[s * 85];
    const float* wp = &sw2[o * 85];
#pragma unroll 4
    for (int k = 0; k < 84; ++k) acc = fmaf(hp[k], wp[k], acc);
    out[(img0 + s) * 10 + o] = acc;
  }
}

extern "C" void kernel_launch(void* const* d_in, const int* in_sizes, int n_in,
                              void* d_out, int out_size, void* d_ws,
                              size_t ws_size, hipStream_t stream) {
  const float* x = (const float*)d_in[0];
  const float* conv1_w = (const float*)d_in[1];
  const float* conv1_b = (const float*)d_in[2];
  const float* conv2_w = (const float*)d_in[3];
  const float* conv2_b = (const float*)d_in[4];
  const float* bn2_g = (const float*)d_in[5];
  const float* bn2_b = (const float*)d_in[6];
  const float* conv3_w = (const float*)d_in[7];
  const float* conv3_b = (const float*)d_in[8];
  const float* bn3_g = (const float*)d_in[9];
  const float* bn3_b = (const float*)d_in[10];
  const float* fc1_w = (const float*)d_in[11];
  const float* fc1_b = (const float*)d_in[12];
  const float* fc2_w = (const float*)d_in[13];
  const float* fc2_b = (const float*)d_in[14];
  float* out = (float*)d_out;

  double* sums = (double*)d_ws;
  float* fbase = (float*)((char*)d_ws + DBL_BYTES);
  float* scales = fbase;
  float* w2t = fbase + W2B_OFF;
  float* w3bT = fbase + W3BT_OFF;
  float* f1b = fbase + FC1B_OFF;
  float* m1 = fbase + H1_OFF;
  float* m2 = fbase + H2_OFF;
  float* y3 = fbase + Y3_OFF;

  hipMemsetAsync(d_ws, 0, DBL_BYTES, stream);
  binarize_k<<<188, 256, 0, stream>>>(conv2_w, conv3_w, fc1_w, w2t, w3bT, f1b);

  conv1_fused<<<1024, 256, 0, stream>>>(x, conv1_w, conv1_b, m1, sums);
  finalize_bn<<<1, 128, 0, stream>>>(sums + SUM1, sums + SQ1, 6,
                                     1.0 / (8192.0 * 784.0), 1e-4, nullptr,
                                     nullptr, scales + A1, scales + C1);

  conv2_fused<<<1024, 256, 0, stream>>>(m1, w2t, conv2_b, scales, m2, sums);
  finalize_bn<<<1, 128, 0, stream>>>(sums + SUM2, sums + SQ2, 16,
                                     1.0 / (8192.0 * 100.0), 1e-4, bn2_g, bn2_b,
                                     scales + A2, scales + C2);

  conv3_gemm<<<256, 256, 0, stream>>>(m2, w3bT, conv3_b, scales, y3, sums);
  finalize_bn<<<1, 128, 0, stream>>>(sums + SUM3, sums + SQ3, 120,
                                     1.0 / 8192.0, 1e-5, bn3_g, bn3_b,
                                     scales + A3, scales + C3);

  fc_fused<<<256, 256, 0, stream>>>(y3, scales, f1b, fc1_b, fc2_w, fc2_b, out);
}

// Round 6
// 293.562 us; speedup vs baseline: 2.8584x; 1.0204x over previous
//
#include <hip/hip_runtime.h>

#define DEVFN __device__ __forceinline__

DEVFN float sgnf(float x) { return (x > 0.f) ? 1.f : ((x < 0.f) ? -1.f : 0.f); }

// ---- workspace layout ----
// double region (BN stat accumulators, 64 contention slots per channel)
#define SUM1 0        // 6*64 doubles
#define SQ1  384
#define SUM2 768      // 16*64
#define SQ2  1792
#define SUM3 2816     // 120*64
#define SQ3  10496
#define DBL_BYTES 145408  // 18176 doubles

// float region offsets (in floats, from fbase = ws + DBL_BYTES)
#define A1 0
#define C1 8
#define A2 16
#define C2 32
#define A3 48
#define C3 168
#define W2B_OFF  512                    // 2400: w2 binarized, layout [ci][k][ch16]
#define W3BT_OFF 3584                   // 48000, layout [400][120]
#define FC1B_OFF 51584                  // 10080
#define H1_OFF   65536                  // 8192*1176 (pooled pre-BN layer1)
#define H2_OFF   (H1_OFF + 8192*1176)   // 8192*400  (pooled pre-BN layer2; BN2 applied on load in conv3)
#define Y3_OFF   (H2_OFF + 8192*400)    // 8192*120  (pre-BN layer3)

// ---------------- binarize weights ----------------
__global__ __launch_bounds__(256) void binarize_k(
    const float* __restrict__ w2, const float* __restrict__ w3,
    const float* __restrict__ f1, float* __restrict__ w2t,
    float* __restrict__ w3bT, float* __restrict__ f1b) {
  int i = blockIdx.x * 256 + threadIdx.x;
  if (i < 2400) {  // [ci][k][ch]: i = ci*400 + k*16 + ch
    int ci = i / 400, r = i - ci * 400;
    int k = r >> 4, ch = r & 15;
    w2t[i] = sgnf(w2[(ch * 6 + ci) * 25 + k]);
  }
  if (i < 48000) {
    int c = i / 400, j = i - c * 400;
    w3bT[j * 120 + c] = sgnf(w3[i]);  // transpose for coalesced conv3 reads
  }
  if (i < 10080) f1b[i] = sgnf(f1[i]);
}

// ---------------- layer 1 fused: conv + stats + pre-BN maxpool ----------------
// thread-task = (img, ch, pool-row py): 2 output rows x 28 cols, pooled to 14.
__global__ __launch_bounds__(256, 3) void conv1_fused(
    const float* __restrict__ x, const float* __restrict__ w1,
    const float* __restrict__ b1, float* __restrict__ m1,
    double* __restrict__ sums) {
  __shared__ float simg[8 * 1088];   // row stride 34 (bank-conflict pad)
  __shared__ float swtp[6 * 40];     // padded weights, stride 40
  __shared__ float red[6], redq[6];
  int tid = threadIdx.x;
  int img0 = blockIdx.x * 8;
  {
    const float2* xg = (const float2*)(x + (size_t)img0 * 1024);
    for (int i2 = tid; i2 < 4096; i2 += 256) {
      int img = i2 >> 9;
      int r = (i2 >> 4) & 31;
      int c2 = i2 & 15;
      *(float2*)&simg[img * 1088 + r * 34 + c2 * 2] = xg[i2];
    }
  }
  for (int i = tid; i < 240; i += 256) {
    int ch = i / 40, k = i - ch * 40;
    swtp[i] = (k < 25) ? w1[ch * 25 + k] : 0.f;
  }
  if (tid < 6) { red[tid] = 0.f; redq[tid] = 0.f; }
  __syncthreads();

  for (int idx = tid; idx < 672; idx += 256) {
    int img = idx / 84;
    int r = idx - img * 84;
    int ch = r / 14;
    int py = r - ch * 14;
    float wr[25];
    {
      const float4* wp = (const float4*)&swtp[ch * 40];
#pragma unroll
      for (int t = 0; t < 6; ++t) {
        float4 v = wp[t];
        wr[4 * t] = v.x; wr[4 * t + 1] = v.y; wr[4 * t + 2] = v.z; wr[4 * t + 3] = v.w;
      }
      wr[24] = swtp[ch * 40 + 24];
    }
    float bb = b1[ch];
    float acc0[28], acc1[28];
#pragma unroll
    for (int o = 0; o < 28; ++o) { acc0[o] = bb; acc1[o] = bb; }
#pragma unroll
    for (int d = 0; d < 6; ++d) {
      int row = 2 * py + d;
      float rb[32];
      const float2* rp = (const float2*)&simg[img * 1088 + row * 34];
#pragma unroll
      for (int t = 0; t < 16; ++t) { float2 v = rp[t]; rb[2 * t] = v.x; rb[2 * t + 1] = v.y; }
      if (d < 5) {
#pragma unroll
        for (int kx = 0; kx < 5; ++kx) {
          float w = wr[d * 5 + kx];
#pragma unroll
          for (int o = 0; o < 28; ++o) acc0[o] = fmaf(rb[o + kx], w, acc0[o]);
        }
      }
      if (d >= 1) {
#pragma unroll
        for (int kx = 0; kx < 5; ++kx) {
          float w = wr[(d - 1) * 5 + kx];
#pragma unroll
          for (int o = 0; o < 28; ++o) acc1[o] = fmaf(rb[o + kx], w, acc1[o]);
        }
      }
    }
    float s = 0.f, s2 = 0.f;
#pragma unroll
    for (int o = 0; o < 28; ++o) {
      s += acc0[o] + acc1[o];
      s2 = fmaf(acc0[o], acc0[o], s2);
      s2 = fmaf(acc1[o], acc1[o], s2);
    }
    atomicAdd(&red[ch], s);
    atomicAdd(&redq[ch], s2);
    float* mp = m1 + (size_t)(img0 + img) * 1176 + ch * 196 + py * 14;
#pragma unroll
    for (int j = 0; j < 7; ++j) {
      float2 v;
      v.x = fmaxf(fmaxf(acc0[4 * j], acc0[4 * j + 1]), fmaxf(acc1[4 * j], acc1[4 * j + 1]));
      v.y = fmaxf(fmaxf(acc0[4 * j + 2], acc0[4 * j + 3]), fmaxf(acc1[4 * j + 2], acc1[4 * j + 3]));
      *(float2*)&mp[2 * j] = v;
    }
  }
  __syncthreads();
  if (tid < 6) {
    int slot = blockIdx.x & 63;
    atomicAdd(&sums[SUM1 + tid * 64 + slot], (double)red[tid]);
    atomicAdd(&sums[SQ1 + tid * 64 + slot], (double)redq[tid]);
  }
}

// ---------------- BN finalize: a = g*rsqrt(var+eps), c = beta - mean*a ------
__global__ __launch_bounds__(128) void finalize_bn(
    const double* __restrict__ sum, const double* __restrict__ sq, int nch,
    double invN, double eps, const float* __restrict__ gamma,
    const float* __restrict__ beta, float* __restrict__ a,
    float* __restrict__ c) {
  int ch = threadIdx.x;
  if (ch >= nch) return;
  double s = 0.0, q = 0.0;
  for (int k = 0; k < 64; ++k) {
    s += sum[ch * 64 + k];
    q += sq[ch * 64 + k];
  }
  double mean = s * invN;
  double var = q * invN - mean * mean;
  float inv = (float)(1.0 / sqrt(var + eps));
  float g = gamma ? fmaxf(gamma[ch], 0.01f) : 1.f;
  float av = g * inv;
  float cv = (beta ? beta[ch] : 0.f) - (float)mean * av;
  a[ch] = av;
  c[ch] = cv;
}

// ---------------- layer 2 fused: BN1+relu on load, conv + stats + pre-BN pool
// block 320 = 16ch x 4img x 5pr (each wave = one pr, 16ch x 4img).
// Activation reads: 16-lane broadcast, img stride 1352 (== 8 mod 32) -> the 4
// img groups hit disjoint bank quads {0,8,16,24}: conflict-free b128.
// Weight reads: [ci][k][ch16] layout -> 16 consecutive banks, 4-way broadcast.
// One pr per thread: weights read once per ci (not per pooled row).
__global__ __launch_bounds__(320, 5) void conv2_fused(
    const float* __restrict__ m1, const float* __restrict__ w2t,
    const float* __restrict__ b2, const float* __restrict__ scales,
    float* __restrict__ m2, double* __restrict__ sums) {
  __shared__ float sh1[4 * 1352];   // 4 img x (6 pl x 14 rows x 16 pad) + 8
  __shared__ float swt[2400];       // [ci][k][ch16]
  __shared__ float sa1[6], sc1[6];
  __shared__ float red[16], redq[16];
  int tid = threadIdx.x;
  int img0 = blockIdx.x * 4;
  if (tid < 6) { sa1[tid] = scales[A1 + tid]; sc1[tid] = scales[C1 + tid]; }
  if (tid < 16) { red[tid] = 0.f; redq[tid] = 0.f; }
  __syncthreads();
  {
    const float4* wg = (const float4*)w2t;
    float4* w4 = (float4*)swt;
    for (int i4 = tid; i4 < 600; i4 += 320) w4[i4] = wg[i4];
  }
  {
    const float2* mg = (const float2*)(m1 + (size_t)img0 * 1176);
    for (int i2 = tid; i2 < 2352; i2 += 320) {
      int img = i2 / 588;
      int r = i2 - img * 588;
      int pl = r / 98;
      int rr = r - pl * 98;
      int row = rr / 7, t = rr - row * 7;
      float a = sa1[pl], c = sc1[pl];
      float2 v = mg[i2];
      v.x = fmaxf(fmaf(a, v.x, c), 0.f);
      v.y = fmaxf(fmaf(a, v.y, c), 0.f);
      *(float2*)&sh1[img * 1352 + pl * 224 + row * 16 + t * 2] = v;
    }
  }
  __syncthreads();

  int ch = tid & 15;
  int img = (tid >> 4) & 3;
  int pr = tid >> 6;  // 0..4, uniform per wave
  float bb = b2[ch];
  float acc[2][10];
#pragma unroll
  for (int o = 0; o < 10; ++o) { acc[0][o] = bb; acc[1][o] = bb; }
  const float* ibase = &sh1[img * 1352];
  for (int ci = 0; ci < 6; ++ci) {
    float w[25];
#pragma unroll
    for (int k = 0; k < 25; ++k) w[k] = swt[ci * 400 + k * 16 + ch];
    const float* rbase = ibase + ci * 224 + pr * 32;
#pragma unroll
    for (int d = 0; d < 6; ++d) {
      float rb[16];
      const float4* rp = (const float4*)(rbase + d * 16);
#pragma unroll
      for (int t = 0; t < 4; ++t) {
        float4 v = rp[t];
        rb[4 * t] = v.x; rb[4 * t + 1] = v.y; rb[4 * t + 2] = v.z; rb[4 * t + 3] = v.w;
      }
      if (d < 5) {
#pragma unroll
        for (int kx = 0; kx < 5; ++kx) {
          float wv = w[d * 5 + kx];
#pragma unroll
          for (int o = 0; o < 10; ++o) acc[0][o] = fmaf(rb[o + kx], wv, acc[0][o]);
        }
      }
      if (d >= 1) {
#pragma unroll
        for (int kx = 0; kx < 5; ++kx) {
          float wv = w[(d - 1) * 5 + kx];
#pragma unroll
          for (int o = 0; o < 10; ++o) acc[1][o] = fmaf(rb[o + kx], wv, acc[1][o]);
        }
      }
    }
  }
  float s0 = 0.f, q0 = 0.f;
#pragma unroll
  for (int rr2 = 0; rr2 < 2; ++rr2)
#pragma unroll
    for (int o = 0; o < 10; ++o) {
      float v = acc[rr2][o];
      s0 += v;
      q0 = fmaf(v, v, q0);
    }
  {
    float* mpo = m2 + (size_t)(img0 + img) * 400 + ch * 25 + pr * 5;
#pragma unroll
    for (int pc = 0; pc < 5; ++pc)
      mpo[pc] = fmaxf(fmaxf(acc[0][2 * pc], acc[0][2 * pc + 1]),
                      fmaxf(acc[1][2 * pc], acc[1][2 * pc + 1]));
  }
  // reduce stats over the 4 img lane-groups of this wave, 16 atomics/wave
  s0 += __shfl_xor(s0, 16, 64); q0 += __shfl_xor(q0, 16, 64);
  s0 += __shfl_xor(s0, 32, 64); q0 += __shfl_xor(q0, 32, 64);
  if ((tid & 48) == 0) {
    atomicAdd(&red[ch], s0);
    atomicAdd(&redq[ch], q0);
  }
  __syncthreads();
  if (tid < 16) {
    int slot = blockIdx.x & 63;
    atomicAdd(&sums[SUM2 + tid * 64 + slot], (double)red[tid]);
    atomicAdd(&sums[SQ2 + tid * 64 + slot], (double)redq[tid]);
  }
}

// ---------------- layer 3: LDS-tiled GEMM, BN2+relu fused on A-load, + stats
// grid 256, block 256. M-tile=32 imgs, N=120 (pad 128), K=400 in 4 chunks.
// per-thread 4 imgs x 4 ch register tile. A stored k-major for b128 reads.
__global__ __launch_bounds__(256) void conv3_gemm(
    const float* __restrict__ m2, const float* __restrict__ w3bT,
    const float* __restrict__ b3, const float* __restrict__ scales,
    float* __restrict__ y3, double* __restrict__ sums) {
  __shared__ float sA[100 * 36];    // [k][img], img-dim padded 32->36
  __shared__ float sB[100 * 128];   // [k][ch], ch padded 120->128 (zeros)
  __shared__ float red[128], redq[128];
  __shared__ float sa2[16], sc2[16];
  int tid = threadIdx.x;
  int img0 = blockIdx.x * 32;
  if (tid < 128) { red[tid] = 0.f; redq[tid] = 0.f; }
  if (tid >= 128 && tid < 144) {
    sa2[tid - 128] = scales[A2 + tid - 128];
    sc2[tid - 128] = scales[C2 + tid - 128];
  }
  int tx = tid & 31, ty = tid >> 5;
  int c0 = tx * 4;
  float acc[4][4] = {};
  for (int kc = 0; kc < 400; kc += 100) {
    __syncthreads();  // also covers sa2/red init before first staging
    // stage A: 32 imgs x 100 k, transpose to k-major, BN2+relu applied
    for (int i4 = tid; i4 < 800; i4 += 256) {
      int i = i4 / 25, t = i4 - i * 25;
      float4 v = *(const float4*)(m2 + (size_t)(img0 + i) * 400 + kc + t * 4);
      int jj = t * 4;
      float vv[4] = {v.x, v.y, v.z, v.w};
#pragma unroll
      for (int e = 0; e < 4; ++e) {
        int ch = (kc + jj + e) / 25;
        sA[(jj + e) * 36 + i] = fmaxf(fmaf(sa2[ch], vv[e], sc2[ch]), 0.f);
      }
    }
    // stage B: 100 k x 120 ch (+8 zero pad)
    for (int i4 = tid; i4 < 3200; i4 += 256) {
      int j = i4 >> 5, c4 = i4 & 31;
      float4 v;
      if (c4 < 30)
        v = *(const float4*)(w3bT + (size_t)(kc + j) * 120 + c4 * 4);
      else
        v = make_float4(0.f, 0.f, 0.f, 0.f);
      *(float4*)(sB + j * 128 + c4 * 4) = v;
    }
    __syncthreads();
#pragma unroll 2
    for (int j = 0; j < 100; ++j) {
      float4 a = *(const float4*)(sA + j * 36 + ty * 4);
      float4 b = *(const float4*)(sB + j * 128 + c0);
      acc[0][0] = fmaf(a.x, b.x, acc[0][0]);
      acc[0][1] = fmaf(a.x, b.y, acc[0][1]);
      acc[0][2] = fmaf(a.x, b.z, acc[0][2]);
      acc[0][3] = fmaf(a.x, b.w, acc[0][3]);
      acc[1][0] = fmaf(a.y, b.x, acc[1][0]);
      acc[1][1] = fmaf(a.y, b.y, acc[1][1]);
      acc[1][2] = fmaf(a.y, b.z, acc[1][2]);
      acc[1][3] = fmaf(a.y, b.w, acc[1][3]);
      acc[2][0] = fmaf(a.z, b.x, acc[2][0]);
      acc[2][1] = fmaf(a.z, b.y, acc[2][1]);
      acc[2][2] = fmaf(a.z, b.z, acc[2][2]);
      acc[2][3] = fmaf(a.z, b.w, acc[2][3]);
      acc[3][0] = fmaf(a.w, b.x, acc[3][0]);
      acc[3][1] = fmaf(a.w, b.y, acc[3][1]);
      acc[3][2] = fmaf(a.w, b.z, acc[3][2]);
      acc[3][3] = fmaf(a.w, b.w, acc[3][3]);
    }
  }
  // epilogue: +bias, write y3, accumulate stats
  if (c0 < 120) {
    float4 bias = *(const float4*)(b3 + c0);
    float sc[4] = {0.f, 0.f, 0.f, 0.f}, sq[4] = {0.f, 0.f, 0.f, 0.f};
#pragma unroll
    for (int i = 0; i < 4; ++i) {
      float4 v;
      v.x = acc[i][0] + bias.x;
      v.y = acc[i][1] + bias.y;
      v.z = acc[i][2] + bias.z;
      v.w = acc[i][3] + bias.w;
      *(float4*)(y3 + (size_t)(img0 + ty * 4 + i) * 120 + c0) = v;
      sc[0] += v.x; sq[0] = fmaf(v.x, v.x, sq[0]);
      sc[1] += v.y; sq[1] = fmaf(v.y, v.y, sq[1]);
      sc[2] += v.z; sq[2] = fmaf(v.z, v.z, sq[2]);
      sc[3] += v.w; sq[3] = fmaf(v.w, v.w, sq[3]);
    }
#pragma unroll
    for (int c = 0; c < 4; ++c) {
      atomicAdd(&red[c0 + c], sc[c]);
      atomicAdd(&redq[c0 + c], sq[c]);
    }
  }
  __syncthreads();
  if (tid < 120) {
    int slot = blockIdx.x & 63;
    atomicAdd(&sums[SUM3 + tid * 64 + slot], (double)red[tid]);
    atomicAdd(&sums[SQ3 + tid * 64 + slot], (double)redq[tid]);
  }
}

// ---------------- fc1(binary)+relu -> fc2 fused, BN3+relu on load ----------
__global__ __launch_bounds__(256) void fc_fused(
    const float* __restrict__ y3, const float* __restrict__ scales,
    const float* __restrict__ f1b, const float* __restrict__ b1,
    const float* __restrict__ w2, const float* __restrict__ b2,
    float* __restrict__ out) {
  __shared__ float sh3[32 * 121];
  __shared__ float sh4[32 * 85];
  __shared__ float sw2[10 * 85];
  __shared__ float sa3[120], sc3[120];
  __shared__ float sb1[84], sb2[10];
  int tid = threadIdx.x;
  int img0 = blockIdx.x * 32;
  if (tid < 120) { sa3[tid] = scales[A3 + tid]; sc3[tid] = scales[C3 + tid]; }
  if (tid >= 128 && tid < 212) sb1[tid - 128] = b1[tid - 128];
  if (tid >= 216 && tid < 226) sb2[tid - 216] = b2[tid - 216];
  __syncthreads();
  for (int i = tid; i < 32 * 120; i += 256) {
    int s = i / 120, k = i - s * 120;
    sh3[s * 121 + k] = fmaxf(fmaf(sa3[k], y3[(size_t)img0 * 120 + i], sc3[k]), 0.f);
  }
  for (int i = tid; i < 840; i += 256) {
    int o = i / 84, k = i - o * 84;
    sw2[o * 85 + k] = w2[i];
  }
  __syncthreads();
  for (int idx = tid; idx < 32 * 84; idx += 256) {
    int s = idx / 84, j = idx - s * 84;
    float acc = sb1[j];
    const float* wp = f1b + j * 120;
    const float* hp = &sh3[s * 121];
#pragma unroll 4
    for (int k = 0; k < 120; ++k) acc = fmaf(hp[k], wp[k], acc);
    sh4[s * 85 + j] = fmaxf(acc, 0.f);
  }
  __syncthreads();
  for (int idx = tid; idx < 320; idx += 256) {
    int s = idx / 10, o = idx - s * 10;
    float acc = sb2[o];
    const float* hp = &sh4[s * 85];
    const float* wp = &sw2[o * 85];
#pragma unroll 4
    for (int k = 0; k < 84; ++k) acc = fmaf(hp[k], wp[k], acc);
    out[(img0 + s) * 10 + o] = acc;
  }
}

extern "C" void kernel_launch(void* const* d_in, const int* in_sizes, int n_in,
                              void* d_out, int out_size, void* d_ws,
                              size_t ws_size, hipStream_t stream) {
  const float* x = (const float*)d_in[0];
  const float* conv1_w = (const float*)d_in[1];
  const float* conv1_b = (const float*)d_in[2];
  const float* conv2_w = (const float*)d_in[3];
  const float* conv2_b = (const float*)d_in[4];
  const float* bn2_g = (const float*)d_in[5];
  const float* bn2_b = (const float*)d_in[6];
  const float* conv3_w = (const float*)d_in[7];
  const float* conv3_b = (const float*)d_in[8];
  const float* bn3_g = (const float*)d_in[9];
  const float* bn3_b = (const float*)d_in[10];
  const float* fc1_w = (const float*)d_in[11];
  const float* fc1_b = (const float*)d_in[12];
  const float* fc2_w = (const float*)d_in[13];
  const float* fc2_b = (const float*)d_in[14];
  float* out = (float*)d_out;

  double* sums = (double*)d_ws;
  float* fbase = (float*)((char*)d_ws + DBL_BYTES);
  float* scales = fbase;
  float* w2t = fbase + W2B_OFF;
  float* w3bT = fbase + W3BT_OFF;
  float* f1b = fbase + FC1B_OFF;
  float* m1 = fbase + H1_OFF;
  float* m2 = fbase + H2_OFF;
  float* y3 = fbase + Y3_OFF;

  hipMemsetAsync(d_ws, 0, DBL_BYTES, stream);
  binarize_k<<<188, 256, 0, stream>>>(conv2_w, conv3_w, fc1_w, w2t, w3bT, f1b);

  conv1_fused<<<1024, 256, 0, stream>>>(x, conv1_w, conv1_b, m1, sums);
  finalize_bn<<<1, 128, 0, stream>>>(sums + SUM1, sums + SQ1, 6,
                                     1.0 / (8192.0 * 784.0), 1e-4, nullptr,
                                     nullptr, scales + A1, scales + C1);

  conv2_fused<<<2048, 320, 0, stream>>>(m1, w2t, conv2_b, scales, m2, sums);
  finalize_bn<<<1, 128, 0, stream>>>(sums + SUM2, sums + SQ2, 16,
                                     1.0 / (8192.0 * 100.0), 1e-4, bn2_g, bn2_b,
                                     scales + A2, scales + C2);

  conv3_gemm<<<256, 256, 0, stream>>>(m2, w3bT, conv3_b, scales, y3, sums);
  finalize_bn<<<1, 128, 0, stream>>>(sums + SUM3, sums + SQ3, 120,
                                     1.0 / 8192.0, 1e-5, bn3_g, bn3_b,
                                     scales + A3, scales + C3);

  fc_fused<<<256, 256, 0, stream>>>(y3, scales, f1b, fc1_b, fc2_w, fc2_b, out);
}

// Round 7
// 283.014 us; speedup vs baseline: 2.9649x; 1.0373x over previous
//
#include <hip/hip_runtime.h>

#define DEVFN __device__ __forceinline__

DEVFN float sgnf(float x) { return (x > 0.f) ? 1.f : ((x < 0.f) ? -1.f : 0.f); }

// round-to-nearest-even fp32 -> bf16 bits
DEVFN unsigned short f2bf(float x) {
  unsigned int u = __float_as_uint(x);
  unsigned int r = (u + 0x7fffu + ((u >> 16) & 1u)) >> 16;
  return (unsigned short)r;
}

typedef __attribute__((ext_vector_type(8))) short short8;
typedef __attribute__((ext_vector_type(4))) float f32x4;

// ---- workspace layout ----
// double region (BN stat accumulators, 64 contention slots per channel)
#define SUM1 0        // 6*64 doubles
#define SQ1  384
#define SUM2 768      // 16*64
#define SQ2  1792
#define SUM3 2816     // 120*64
#define SQ3  10496
#define DBL_BYTES 145408  // 18176 doubles

// float region offsets (in floats, from fbase = ws + DBL_BYTES)
#define A1 0
#define C1 8
#define A2 16
#define C2 32
#define A3 48
#define C3 168
#define W2B_OFF  512    // 2400: w2 binarized, layout [ci][k][ch16]
#define WFR_OFF  3584   // conv3 weights, bf16 MFMA-frag image: 102400 ushort = 51200 floats
#define F1BT_OFF 54784  // 10080: fc1 binarized TRANSPOSED [120][84]
#define H1_OFF   65536                  // 8192*1176 (pooled pre-BN layer1)
#define H2_OFF   (H1_OFF + 8192*1176)   // 8192*400  (pooled pre-BN layer2)
#define Y3_OFF   (H2_OFF + 8192*400)    // 8192*120  (pre-BN layer3)

// ---------------- binarize / weight-prep ----------------
// wfr frag-image: element i = ((nt*25 + c)*64 + lane)*8 + j holds bf16 of
// W'[k' = c*32 + (lane>>4)*8 + j][ch = nt*16 + (lane&15)], W'[k'] = w3sgn[k'>>1]
// (K duplicated for the hi/lo split trick; ch>=120 zero-padded).
__global__ __launch_bounds__(256) void binarize_k(
    const float* __restrict__ w2, const float* __restrict__ w3,
    const float* __restrict__ f1, float* __restrict__ w2t,
    unsigned short* __restrict__ wfr, float* __restrict__ f1bT) {
  int i = blockIdx.x * 256 + threadIdx.x;
  if (i < 2400) {  // [ci][k][ch]: i = ci*400 + k*16 + ch
    int ci = i / 400, r = i - ci * 400;
    int k = r >> 4, ch = r & 15;
    w2t[i] = sgnf(w2[(ch * 6 + ci) * 25 + k]);
  }
  if (i < 102400) {
    int j = i & 7;
    int t = i >> 3;
    int l = t & 63;
    int cc = (t >> 6) % 25;
    int nt = (t >> 6) / 25;
    int ch = nt * 16 + (l & 15);
    int kp = cc * 32 + ((l >> 4) << 3) + j;
    float v = (ch < 120) ? sgnf(w3[ch * 400 + (kp >> 1)]) : 0.f;
    wfr[i] = f2bf(v);  // exact for -1/0/+1
  }
  if (i < 10080) {
    int j = i / 120, k = i - j * 120;
    f1bT[k * 84 + j] = sgnf(f1[i]);  // transpose: coalesced fc reads
  }
}

// ---------------- layer 1 fused: conv + stats + pre-BN maxpool ----------------
__global__ __launch_bounds__(256, 3) void conv1_fused(
    const float* __restrict__ x, const float* __restrict__ w1,
    const float* __restrict__ b1, float* __restrict__ m1,
    double* __restrict__ sums) {
  __shared__ float simg[8 * 1088];   // row stride 34 (bank-conflict pad)
  __shared__ float swtp[6 * 40];     // padded weights, stride 40
  __shared__ float red[6], redq[6];
  int tid = threadIdx.x;
  int img0 = blockIdx.x * 8;
  {
    const float2* xg = (const float2*)(x + (size_t)img0 * 1024);
    for (int i2 = tid; i2 < 4096; i2 += 256) {
      int img = i2 >> 9;
      int r = (i2 >> 4) & 31;
      int c2 = i2 & 15;
      *(float2*)&simg[img * 1088 + r * 34 + c2 * 2] = xg[i2];
    }
  }
  for (int i = tid; i < 240; i += 256) {
    int ch = i / 40, k = i - ch * 40;
    swtp[i] = (k < 25) ? w1[ch * 25 + k] : 0.f;
  }
  if (tid < 6) { red[tid] = 0.f; redq[tid] = 0.f; }
  __syncthreads();

  for (int idx = tid; idx < 672; idx += 256) {
    int img = idx / 84;
    int r = idx - img * 84;
    int ch = r / 14;
    int py = r - ch * 14;
    float wr[25];
    {
      const float4* wp = (const float4*)&swtp[ch * 40];
#pragma unroll
      for (int t = 0; t < 6; ++t) {
        float4 v = wp[t];
        wr[4 * t] = v.x; wr[4 * t + 1] = v.y; wr[4 * t + 2] = v.z; wr[4 * t + 3] = v.w;
      }
      wr[24] = swtp[ch * 40 + 24];
    }
    float bb = b1[ch];
    float acc0[28], acc1[28];
#pragma unroll
    for (int o = 0; o < 28; ++o) { acc0[o] = bb; acc1[o] = bb; }
#pragma unroll
    for (int d = 0; d < 6; ++d) {
      int row = 2 * py + d;
      float rb[32];
      const float2* rp = (const float2*)&simg[img * 1088 + row * 34];
#pragma unroll
      for (int t = 0; t < 16; ++t) { float2 v = rp[t]; rb[2 * t] = v.x; rb[2 * t + 1] = v.y; }
      if (d < 5) {
#pragma unroll
        for (int kx = 0; kx < 5; ++kx) {
          float w = wr[d * 5 + kx];
#pragma unroll
          for (int o = 0; o < 28; ++o) acc0[o] = fmaf(rb[o + kx], w, acc0[o]);
        }
      }
      if (d >= 1) {
#pragma unroll
        for (int kx = 0; kx < 5; ++kx) {
          float w = wr[(d - 1) * 5 + kx];
#pragma unroll
          for (int o = 0; o < 28; ++o) acc1[o] = fmaf(rb[o + kx], w, acc1[o]);
        }
      }
    }
    float s = 0.f, s2 = 0.f;
#pragma unroll
    for (int o = 0; o < 28; ++o) {
      s += acc0[o] + acc1[o];
      s2 = fmaf(acc0[o], acc0[o], s2);
      s2 = fmaf(acc1[o], acc1[o], s2);
    }
    atomicAdd(&red[ch], s);
    atomicAdd(&redq[ch], s2);
    float* mp = m1 + (size_t)(img0 + img) * 1176 + ch * 196 + py * 14;
#pragma unroll
    for (int j = 0; j < 7; ++j) {
      float2 v;
      v.x = fmaxf(fmaxf(acc0[4 * j], acc0[4 * j + 1]), fmaxf(acc1[4 * j], acc1[4 * j + 1]));
      v.y = fmaxf(fmaxf(acc0[4 * j + 2], acc0[4 * j + 3]), fmaxf(acc1[4 * j + 2], acc1[4 * j + 3]));
      *(float2*)&mp[2 * j] = v;
    }
  }
  __syncthreads();
  if (tid < 6) {
    int slot = blockIdx.x & 63;
    atomicAdd(&sums[SUM1 + tid * 64 + slot], (double)red[tid]);
    atomicAdd(&sums[SQ1 + tid * 64 + slot], (double)redq[tid]);
  }
}

// ---------------- BN finalize: a = g*rsqrt(var+eps), c = beta - mean*a ------
__global__ __launch_bounds__(128) void finalize_bn(
    const double* __restrict__ sum, const double* __restrict__ sq, int nch,
    double invN, double eps, const float* __restrict__ gamma,
    const float* __restrict__ beta, float* __restrict__ a,
    float* __restrict__ c) {
  int ch = threadIdx.x;
  if (ch >= nch) return;
  double s = 0.0, q = 0.0;
  for (int k = 0; k < 64; ++k) {
    s += sum[ch * 64 + k];
    q += sq[ch * 64 + k];
  }
  double mean = s * invN;
  double var = q * invN - mean * mean;
  float inv = (float)(1.0 / sqrt(var + eps));
  float g = gamma ? fmaxf(gamma[ch], 0.01f) : 1.f;
  float av = g * inv;
  float cv = (beta ? beta[ch] : 0.f) - (float)mean * av;
  a[ch] = av;
  c[ch] = cv;
}

// ---------------- layer 2 fused: BN1+relu on load, conv + stats + pre-BN pool
__global__ __launch_bounds__(320, 5) void conv2_fused(
    const float* __restrict__ m1, const float* __restrict__ w2t,
    const float* __restrict__ b2, const float* __restrict__ scales,
    float* __restrict__ m2, double* __restrict__ sums) {
  __shared__ float sh1[4 * 1352];   // 4 img x (6 pl x 14 rows x 16 pad) + 8
  __shared__ float swt[2400];       // [ci][k][ch16]
  __shared__ float sa1[6], sc1[6];
  __shared__ float red[16], redq[16];
  int tid = threadIdx.x;
  int img0 = blockIdx.x * 4;
  if (tid < 6) { sa1[tid] = scales[A1 + tid]; sc1[tid] = scales[C1 + tid]; }
  if (tid < 16) { red[tid] = 0.f; redq[tid] = 0.f; }
  __syncthreads();
  {
    const float4* wg = (const float4*)w2t;
    float4* w4 = (float4*)swt;
    for (int i4 = tid; i4 < 600; i4 += 320) w4[i4] = wg[i4];
  }
  {
    const float2* mg = (const float2*)(m1 + (size_t)img0 * 1176);
    for (int i2 = tid; i2 < 2352; i2 += 320) {
      int img = i2 / 588;
      int r = i2 - img * 588;
      int pl = r / 98;
      int rr = r - pl * 98;
      int row = rr / 7, t = rr - row * 7;
      float a = sa1[pl], c = sc1[pl];
      float2 v = mg[i2];
      v.x = fmaxf(fmaf(a, v.x, c), 0.f);
      v.y = fmaxf(fmaf(a, v.y, c), 0.f);
      *(float2*)&sh1[img * 1352 + pl * 224 + row * 16 + t * 2] = v;
    }
  }
  __syncthreads();

  int ch = tid & 15;
  int img = (tid >> 4) & 3;
  int pr = tid >> 6;  // 0..4, uniform per wave
  float bb = b2[ch];
  float acc[2][10];
#pragma unroll
  for (int o = 0; o < 10; ++o) { acc[0][o] = bb; acc[1][o] = bb; }
  const float* ibase = &sh1[img * 1352];
  for (int ci = 0; ci < 6; ++ci) {
    float w[25];
#pragma unroll
    for (int k = 0; k < 25; ++k) w[k] = swt[ci * 400 + k * 16 + ch];
    const float* rbase = ibase + ci * 224 + pr * 32;
#pragma unroll
    for (int d = 0; d < 6; ++d) {
      float rb[16];
      const float4* rp = (const float4*)(rbase + d * 16);
#pragma unroll
      for (int t = 0; t < 4; ++t) {
        float4 v = rp[t];
        rb[4 * t] = v.x; rb[4 * t + 1] = v.y; rb[4 * t + 2] = v.z; rb[4 * t + 3] = v.w;
      }
      if (d < 5) {
#pragma unroll
        for (int kx = 0; kx < 5; ++kx) {
          float wv = w[d * 5 + kx];
#pragma unroll
          for (int o = 0; o < 10; ++o) acc[0][o] = fmaf(rb[o + kx], wv, acc[0][o]);
        }
      }
      if (d >= 1) {
#pragma unroll
        for (int kx = 0; kx < 5; ++kx) {
          float wv = w[(d - 1) * 5 + kx];
#pragma unroll
          for (int o = 0; o < 10; ++o) acc[1][o] = fmaf(rb[o + kx], wv, acc[1][o]);
        }
      }
    }
  }
  float s0 = 0.f, q0 = 0.f;
#pragma unroll
  for (int rr2 = 0; rr2 < 2; ++rr2)
#pragma unroll
    for (int o = 0; o < 10; ++o) {
      float v = acc[rr2][o];
      s0 += v;
      q0 = fmaf(v, v, q0);
    }
  {
    float* mpo = m2 + (size_t)(img0 + img) * 400 + ch * 25 + pr * 5;
#pragma unroll
    for (int pc = 0; pc < 5; ++pc)
      mpo[pc] = fmaxf(fmaxf(acc[0][2 * pc], acc[0][2 * pc + 1]),
                      fmaxf(acc[1][2 * pc], acc[1][2 * pc + 1]));
  }
  s0 += __shfl_xor(s0, 16, 64); q0 += __shfl_xor(q0, 16, 64);
  s0 += __shfl_xor(s0, 32, 64); q0 += __shfl_xor(q0, 32, 64);
  if ((tid & 48) == 0) {
    atomicAdd(&red[ch], s0);
    atomicAdd(&redq[ch], q0);
  }
  __syncthreads();
  if (tid < 16) {
    int slot = blockIdx.x & 63;
    atomicAdd(&sums[SUM2 + tid * 64 + slot], (double)red[tid]);
    atomicAdd(&sums[SQ2 + tid * 64 + slot], (double)redq[tid]);
  }
}

// ---------------- layer 3: MFMA bf16-split GEMM + BN2/relu on load + stats
// Exact trick: activations split x = hi + lo (bf16 pair, K'=800 interleaved);
// weights are sign(w) in {-1,0,1} -> EXACT in bf16, duplicated along K'.
// M-tile 16 imgs/block, N=120 (pad 128 -> 8 N-tiles), 4 waves x 2 N-tiles.
// b_frags: coalesced global b128 from the precomputed frag image (L2-hot).
__global__ __launch_bounds__(256) void conv3_mfma(
    const float* __restrict__ m2, const unsigned short* __restrict__ wfr,
    const float* __restrict__ b3, const float* __restrict__ scales,
    float* __restrict__ y3, double* __restrict__ sums) {
  __shared__ unsigned short Alds[16 * 40];  // [img][k'-chunk 32 + 8 pad] bf16
  __shared__ float sa2[16], sc2[16];
  __shared__ float red[128], redq[128];
  int tid = threadIdx.x;
  int img0 = blockIdx.x * 16;
  if (tid < 16) { sa2[tid] = scales[A2 + tid]; sc2[tid] = scales[C2 + tid]; }
  if (tid < 128) { red[tid] = 0.f; redq[tid] = 0.f; }
  int lane = tid & 63;
  int wv = tid >> 6;         // wave 0..3
  int simg = tid >> 4;       // staging: img 0..15
  int skk = tid & 15;        // staging: orig-k within chunk
  int nt0 = wv * 2, nt1 = wv * 2 + 1;
  const short8* bvec = (const short8*)wfr;
  int arow = lane & 15;          // frag M row
  int aoff = (lane >> 4) << 3;   // frag k' offset
  f32x4 acc0 = {0.f, 0.f, 0.f, 0.f}, acc1 = {0.f, 0.f, 0.f, 0.f};
  __syncthreads();
  for (int c = 0; c < 25; ++c) {
    // stage A chunk: orig k = c*16 + skk -> k' pair (hi,lo) packed as u32
    int k = c * 16 + skk;
    float x = m2[(size_t)(img0 + simg) * 400 + k];
    int ch2 = (k * 41) >> 10;  // k/25 for k<400
    float v = fmaxf(fmaf(sa2[ch2], x, sc2[ch2]), 0.f);
    unsigned int hb = f2bf(v);
    float vh = __uint_as_float(hb << 16);
    unsigned int lb = f2bf(v - vh);
    __syncthreads();  // previous chunk's frag reads done
    *(unsigned int*)&Alds[simg * 40 + 2 * skk] = hb | (lb << 16);
    __syncthreads();
    short8 af = *(const short8*)&Alds[arow * 40 + aoff];
    short8 b0 = bvec[(nt0 * 25 + c) * 64 + lane];
    short8 b1 = bvec[(nt1 * 25 + c) * 64 + lane];
    acc0 = __builtin_amdgcn_mfma_f32_16x16x32_bf16(af, b0, acc0, 0, 0, 0);
    acc1 = __builtin_amdgcn_mfma_f32_16x16x32_bf16(af, b1, acc1, 0, 0, 0);
  }
  // epilogue: C[row=(lane>>4)*4+r][col=lane&15]; +bias, y3 write, stats
  int chA = nt0 * 16 + (lane & 15);   // <= 111, always valid
  int chB = nt1 * 16 + (lane & 15);   // may be >= 120 (pad)
  int rbase = img0 + ((lane >> 4) << 2);
  {
    float bias = b3[chA];
    float s = 0.f, q = 0.f;
#pragma unroll
    for (int r = 0; r < 4; ++r) {
      float v = acc0[r] + bias;
      y3[(size_t)(rbase + r) * 120 + chA] = v;
      s += v; q = fmaf(v, v, q);
    }
    atomicAdd(&red[chA], s);
    atomicAdd(&redq[chA], q);
  }
  if (chB < 120) {
    float bias = b3[chB];
    float s = 0.f, q = 0.f;
#pragma unroll
    for (int r = 0; r < 4; ++r) {
      float v = acc1[r] + bias;
      y3[(size_t)(rbase + r) * 120 + chB] = v;
      s += v; q = fmaf(v, v, q);
    }
    atomicAdd(&red[chB], s);
    atomicAdd(&redq[chB], q);
  }
  __syncthreads();
  if (tid < 120) {
    int slot = blockIdx.x & 63;
    atomicAdd(&sums[SUM3 + tid * 64 + slot], (double)red[tid]);
    atomicAdd(&sums[SQ3 + tid * 64 + slot], (double)redq[tid]);
  }
}

// ---------------- fc1(binary)+relu -> fc2 fused, BN3+relu on load ----------
__global__ __launch_bounds__(256) void fc_fused(
    const float* __restrict__ y3, const float* __restrict__ scales,
    const float* __restrict__ f1bT, const float* __restrict__ b1,
    const float* __restrict__ w2, const float* __restrict__ b2,
    float* __restrict__ out) {
  __shared__ float sh3[32 * 121];
  __shared__ float sh4[32 * 85];
  __shared__ float sw2[10 * 85];
  __shared__ float sa3[120], sc3[120];
  __shared__ float sb1[84], sb2[10];
  int tid = threadIdx.x;
  int img0 = blockIdx.x * 32;
  if (tid < 120) { sa3[tid] = scales[A3 + tid]; sc3[tid] = scales[C3 + tid]; }
  if (tid >= 128 && tid < 212) sb1[tid - 128] = b1[tid - 128];
  if (tid >= 216 && tid < 226) sb2[tid - 216] = b2[tid - 216];
  __syncthreads();
  for (int i = tid; i < 32 * 120; i += 256) {
    int s = i / 120, k = i - s * 120;
    sh3[s * 121 + k] = fmaxf(fmaf(sa3[k], y3[(size_t)img0 * 120 + i], sc3[k]), 0.f);
  }
  for (int i = tid; i < 840; i += 256) {
    int o = i / 84, k = i - o * 84;
    sw2[o * 85 + k] = w2[i];
  }
  __syncthreads();
  for (int idx = tid; idx < 32 * 84; idx += 256) {
    int s = idx / 84, j = idx - s * 84;
    float acc = sb1[j];
    const float* wp = f1bT + j;  // [k][j] layout: coalesced across lanes
    const float* hp = &sh3[s * 121];
#pragma unroll 4
    for (int k = 0; k < 120; ++k) acc = fmaf(hp[k], wp[k * 84], acc);
    sh4[s * 85 + j] = fmaxf(acc, 0.f);
  }
  __syncthreads();
  for (int idx = tid; idx < 320; idx += 256) {
    int s = idx / 10, o = idx - s * 10;
    float acc = sb2[o];
    const float* hp = &sh4[s * 85];
    const float* wp = &sw2[o * 85];
#pragma unroll 4
    for (int k = 0; k < 84; ++k) acc = fmaf(hp[k], wp[k], acc);
    out[(img0 + s) * 10 + o] = acc;
  }
}

extern "C" void kernel_launch(void* const* d_in, const int* in_sizes, int n_in,
                              void* d_out, int out_size, void* d_ws,
                              size_t ws_size, hipStream_t stream) {
  const float* x = (const float*)d_in[0];
  const float* conv1_w = (const float*)d_in[1];
  const float* conv1_b = (const float*)d_in[2];
  const float* conv2_w = (const float*)d_in[3];
  const float* conv2_b = (const float*)d_in[4];
  const float* bn2_g = (const float*)d_in[5];
  const float* bn2_b = (const float*)d_in[6];
  const float* conv3_w = (const float*)d_in[7];
  const float* conv3_b = (const float*)d_in[8];
  const float* bn3_g = (const float*)d_in[9];
  const float* bn3_b = (const float*)d_in[10];
  const float* fc1_w = (const float*)d_in[11];
  const float* fc1_b = (const float*)d_in[12];
  const float* fc2_w = (const float*)d_in[13];
  const float* fc2_b = (const float*)d_in[14];
  float* out = (float*)d_out;

  double* sums = (double*)d_ws;
  float* fbase = (float*)((char*)d_ws + DBL_BYTES);
  float* scales = fbase;
  float* w2t = fbase + W2B_OFF;
  unsigned short* wfr = (unsigned short*)(fbase + WFR_OFF);
  float* f1bT = fbase + F1BT_OFF;
  float* m1 = fbase + H1_OFF;
  float* m2 = fbase + H2_OFF;
  float* y3 = fbase + Y3_OFF;

  hipMemsetAsync(d_ws, 0, DBL_BYTES, stream);
  binarize_k<<<400, 256, 0, stream>>>(conv2_w, conv3_w, fc1_w, w2t, wfr, f1bT);

  conv1_fused<<<1024, 256, 0, stream>>>(x, conv1_w, conv1_b, m1, sums);
  finalize_bn<<<1, 128, 0, stream>>>(sums + SUM1, sums + SQ1, 6,
                                     1.0 / (8192.0 * 784.0), 1e-4, nullptr,
                                     nullptr, scales + A1, scales + C1);

  conv2_fused<<<2048, 320, 0, stream>>>(m1, w2t, conv2_b, scales, m2, sums);
  finalize_bn<<<1, 128, 0, stream>>>(sums + SUM2, sums + SQ2, 16,
                                     1.0 / (8192.0 * 100.0), 1e-4, bn2_g, bn2_b,
                                     scales + A2, scales + C2);

  conv3_mfma<<<512, 256, 0, stream>>>(m2, wfr, conv3_b, scales, y3, sums);
  finalize_bn<<<1, 128, 0, stream>>>(sums + SUM3, sums + SQ3, 120,
                                     1.0 / 8192.0, 1e-5, bn3_g, bn3_b,
                                     scales + A3, scales + C3);

  fc_fused<<<256, 256, 0, stream>>>(y3, scales, f1bT, fc1_b, fc2_w, fc2_b, out);
}